// Round 20
// baseline (177.701 us; speedup 1.0000x reference)
//
#include <hip/hip_runtime.h>
#include <hip/hip_bf16.h>

#define BB 8
#define EMBED 384
#define NH 32
#define HD 12
#define HWN 1024
#define HIDDEN 512
#define KTOT 1536
#define SCALE 0.28867513459481287f

typedef __attribute__((ext_vector_type(8))) unsigned short ushort8;
typedef __attribute__((ext_vector_type(8))) short short8;
typedef __attribute__((ext_vector_type(4))) float f32x4;
typedef __attribute__((ext_vector_type(16))) float f32x16;
typedef __attribute__((ext_vector_type(4))) unsigned short ushort4v;
typedef __attribute__((ext_vector_type(2))) unsigned int uint2v;

static __device__ __forceinline__ float bf2f(unsigned short u) {
    return __uint_as_float(((unsigned int)u) << 16);
}
static __device__ __forceinline__ unsigned short f2bf(float f) {
    unsigned int u = __float_as_uint(f);
    u = u + 0x7FFFu + ((u >> 16) & 1u);   // RNE
    return (unsigned short)(u >> 16);
}
static __device__ __forceinline__ unsigned int cvt_pk_bf16(float lo, float hi) {
    unsigned int r;
    asm("v_cvt_pk_bf16_f32 %0, %1, %2" : "=v"(r) : "v"(lo), "v"(hi));
    return r;
}

#if __has_builtin(__builtin_amdgcn_global_load_lds)
#define HAVE_GLOAD_LDS 1
static __device__ __forceinline__ void gl_lds16(const unsigned short* g, unsigned short* l) {
    __builtin_amdgcn_global_load_lds(
        (const __attribute__((address_space(1))) unsigned int*)g,
        (__attribute__((address_space(3))) unsigned int*)l, 16, 0, 0);
}
#else
#define HAVE_GLOAD_LDS 0
#endif

// ---------------- f32 -> bf16 weights; Wo duplicated into Wo2[512][1536] ----------------
struct WConv {
    const float* src[7];
    unsigned short* dst[7];
    int start[8];   // prefix over vec4 counts
};

__global__ __launch_bounds__(256) void k_bf16_all(WConv wc) {
    int i = blockIdx.x * 256 + threadIdx.x;
    if (i >= wc.start[7]) return;
    int p = 0;
#pragma unroll
    for (int j = 1; j < 7; ++j) p += (i >= wc.start[j]);
    const int e = i - wc.start[p];
    const f32x4 v = reinterpret_cast<const f32x4*>(wc.src[p])[e];
    ushort4v o;
#pragma unroll
    for (int j = 0; j < 4; ++j) o[j] = f2bf(v[j]);
    if (p == 6) {
        const int row = e / 192, cc = e % 192;
        ushort4v* d = reinterpret_cast<ushort4v*>(wc.dst[6]);
        d[row * 384 + cc] = o;
        d[row * 384 + 192 + cc] = o;
    } else {
        reinterpret_cast<ushort4v*>(wc.dst[p])[e] = o;
    }
}

// ---------------- transpose x (B,C,HW) f32 -> fused2[b][n][768 + s*384 + c] bf16 ----------------
__global__ __launch_bounds__(256) void k_transpose(const float* __restrict__ x0, const float* __restrict__ x1,
                                                   unsigned short* __restrict__ fused2) {
    __shared__ float tile[32][33];
    const int z = blockIdx.z;
    const int s = z >> 3, b = z & 7;
    const float* src = (s ? x1 : x0) + (size_t)b * EMBED * HWN;
    unsigned short* dst = fused2 + (size_t)b * HWN * KTOT + 768 + s * 384;
    const int c0 = blockIdx.x * 32;
    const int n0 = blockIdx.y * 32;
    const int tc = threadIdx.x & 31;
    const int tr = threadIdx.x >> 5;
#pragma unroll
    for (int p = 0; p < 4; ++p) {
        int r = tr + p * 8;
        tile[r][tc] = src[(size_t)(c0 + r) * HWN + n0 + tc];
    }
    __syncthreads();
#pragma unroll
    for (int p = 0; p < 4; ++p) {
        int r = tr + p * 8;
        dst[(size_t)(n0 + r) * KTOT + c0 + tc] = f2bf(tile[tc][r]);
    }
}

// ---------------- bf16 MFMA GEMM 128x128xBK64 (m97 structure) ----------------
template <bool F32OUT>
static __device__ __forceinline__ void gemm128(const unsigned short* __restrict__ A, int lda,
                                               const unsigned short* __restrict__ Bt, int ldb,
                                               const float* __restrict__ bias,
                                               unsigned short* __restrict__ outBf,
                                               float* __restrict__ outF,
                                               int K, int bx, int by) {
    __shared__ unsigned short As[128][64];
    __shared__ unsigned short Bs[128][64];
    const int t = threadIdx.x;
    const int lane = t & 63;
    const int w = t >> 6;
    const int wr = w >> 1, wc = w & 1;
    const int o0 = bx * 128, n0 = by * 128;
    const int srow = lane >> 3;
    const int scol = (lane & 7) * 8;

    f32x4 acc[4][4] = {};

    for (int k0 = 0; k0 < K; k0 += 64) {
#pragma unroll
        for (int i = 0; i < 4; ++i) {
            const int c = w * 4 + i;
            const int r = c * 8 + srow;
#if HAVE_GLOAD_LDS
            gl_lds16(A + (size_t)(o0 + r) * lda + k0 + scol, &As[c * 8][0]);
            gl_lds16(Bt + (size_t)(n0 + r) * ldb + k0 + scol, &Bs[c * 8][0]);
#else
            *reinterpret_cast<ushort8*>(&As[r][scol]) =
                *reinterpret_cast<const ushort8*>(A + (size_t)(o0 + r) * lda + k0 + scol);
            *reinterpret_cast<ushort8*>(&Bs[r][scol]) =
                *reinterpret_cast<const ushort8*>(Bt + (size_t)(n0 + r) * ldb + k0 + scol);
#endif
        }
        __syncthreads();
#pragma unroll
        for (int kk = 0; kk < 2; ++kk) {
            const int ko = kk * 32 + ((lane >> 4) << 3);
            short8 af[4], bf[4];
#pragma unroll
            for (int i = 0; i < 4; ++i) {
                af[i] = *reinterpret_cast<const short8*>(&As[wr * 64 + i * 16 + (lane & 15)][ko]);
                bf[i] = *reinterpret_cast<const short8*>(&Bs[wc * 64 + i * 16 + (lane & 15)][ko]);
            }
#pragma unroll
            for (int i = 0; i < 4; ++i)
#pragma unroll
                for (int j = 0; j < 4; ++j)
                    acc[i][j] = __builtin_amdgcn_mfma_f32_16x16x32_bf16(af[i], bf[j], acc[i][j], 0, 0, 0);
        }
        __syncthreads();
    }
#pragma unroll
    for (int i = 0; i < 4; ++i) {
#pragma unroll
        for (int j = 0; j < 4; ++j) {
            const int ob = o0 + wr * 64 + i * 16 + ((lane >> 4) << 2);
            const int n  = n0 + wc * 64 + j * 16 + (lane & 15);
#pragma unroll
            for (int r = 0; r < 4; ++r) {
                const int o = ob + r;
                float v = acc[i][j][r] + bias[o];
                if constexpr (F32OUT) outF[(size_t)o * HWN + n] = v;
                else                  outBf[(size_t)o * HWN + n] = f2bf(v);
            }
        }
    }
}

struct QkvTable {
    const unsigned short* W[6];
    const float* bias[6];
    const unsigned short* fused2;
    unsigned short* out[6];
};

__global__ __launch_bounds__(256) void k_gemm_qkv(QkvTable tab) {
    const int z = blockIdx.z;
    const int b = z / 6, p = z % 6;
    const unsigned short* Bt = tab.fused2 + (size_t)b * HWN * KTOT + 768 + (p / 3) * 384;
    gemm128<false>(tab.W[p], EMBED, Bt, KTOT, tab.bias[p],
                   tab.out[p] + (size_t)b * EMBED * HWN, nullptr,
                   EMBED, blockIdx.x, blockIdx.y);
}

__global__ __launch_bounds__(256) void k_gemm_out(const unsigned short* __restrict__ Wo2,
                                                  const unsigned short* __restrict__ fused2,
                                                  const float* __restrict__ bo,
                                                  float* __restrict__ out) {
    const int b = blockIdx.z;
    gemm128<true>(Wo2, KTOT, fused2 + (size_t)b * HWN * KTOT, KTOT, bo,
                  nullptr, out + (size_t)b * HIDDEN * HWN,
                  KTOT, blockIdx.x, blockIdx.y);
}

// ---------------- MFMA flash attention v9: v8 + 1-deep mc software pipeline ----------------
// QKT(mc+1) issues BEFORE exp/cvt/PV(mc): legal (whole phase's K is in LDS), so the exp chain
// consumes scores computed a full iteration earlier -- QKT MFMA latency fully hidden.
#define OT_STRIDE 416
__global__ __launch_bounds__(256) void k_attn_mfma(const unsigned short* __restrict__ qc,
                                                   const unsigned short* __restrict__ kc,
                                                   const unsigned short* __restrict__ vc,
                                                   const unsigned short* __restrict__ qcb,
                                                   const unsigned short* __restrict__ kcb,
                                                   const unsigned short* __restrict__ vcb,
                                                   unsigned short* __restrict__ fused2) {
    __shared__ unsigned short Ks[256][18];   // [m][d 0..15 + 2 pad], 36B rows (9 dw, coprime 32)
    __shared__ unsigned short Vs[13][264];   // [d][m], row 12 = ones

    const int bid = blockIdx.x;
    const int inst = bid & 511, qt = bid >> 9;
    const int branch = inst >> 8, b = (inst >> 5) & 7, h = inst & 31;
    const unsigned short* Qg = branch ? qc : qcb;
    const unsigned short* Kg = branch ? kcb : kc;
    const unsigned short* Vg = branch ? vcb : vc;
    const int coff = branch ? 384 : 0;
    const size_t base = ((size_t)b * EMBED + h * HD) * HWN;
    const int t = threadIdx.x;
    const int lane = t & 63, w = t >> 6;
    const int q31 = lane & 31, hi = lane >> 5;
    const int n0 = qt * 256;
    const float C2 = SCALE * 1.4426950408889634f;

    // Q B-frags (32x32x16): frag i -> q = n0 + i*128 + w*32 + q31, pre-scaled by C2
    short8 qf[2] = {};
#pragma unroll
    for (int i = 0; i < 2; ++i) {
        const int qg = n0 + i * 128 + w * 32 + q31;
#pragma unroll
        for (int j = 0; j < 8; ++j) {
            const int d = hi * 8 + j;
            if (d < HD)
                qf[i][j] = (short)f2bf(bf2f(Qg[base + (size_t)d * HWN + qg]) * C2);
        }
    }

    f32x16 acc[2], z16;
#pragma unroll
    for (int r = 0; r < 16; ++r) { acc[0][r] = 0.f; acc[1][r] = 0.f; z16[r] = 0.f; }
    const int vrow = (q31 < HD) ? q31 : 12;

    for (int phase = 0; phase < 4; ++phase) {
        const int m0 = phase << 8;
        __syncthreads();
        // --- stage K (256 m): wave w owns d-rows 4w..4w+3 (w=3 -> zeros)
        {
            const size_t kb = base + (size_t)(4 * w) * HWN + m0;
#pragma unroll
            for (int it = 0; it < 4; ++it) {
                const int m = it * 64 + lane;
                unsigned int da = 0, db = 0;
                if (w < 3) {
                    da = (unsigned int)Kg[kb + m] | ((unsigned int)Kg[kb + HWN + m] << 16);
                    db = (unsigned int)Kg[kb + 2 * HWN + m] | ((unsigned int)Kg[kb + 3 * HWN + m] << 16);
                }
                unsigned int* p = reinterpret_cast<unsigned int*>(&Ks[m][w * 4]);
                p[0] = da;
                p[1] = db;
            }
        }
        // --- stage V (256 m)
        if (w < 3) {
#pragma unroll
            for (int r2 = 0; r2 < 2; ++r2) {
                const int d = 4 * w + 2 * r2 + (lane >> 5);
                const int col = (lane & 31) * 8;
                *reinterpret_cast<ushort8*>(&Vs[d][col]) =
                    *reinterpret_cast<const ushort8*>(&Vg[base + (size_t)d * HWN + m0 + col]);
            }
        } else if (lane < 32) {
            ushort8 ones;
#pragma unroll
            for (int j = 0; j < 8; ++j) ones[j] = 0x3F80;
            *reinterpret_cast<ushort8*>(&Vs[12][lane * 8]) = ones;
        }
        __syncthreads();

        // K A-frag loader (dword pairs, 36B rows)
        auto loadK = [&](int mc) -> short8 {
            union { short8 v; unsigned int u[4]; } kf;
            const unsigned int* kp = reinterpret_cast<const unsigned int*>(&Ks[(mc << 5) + q31][hi * 8]);
            kf.u[0] = kp[0]; kf.u[1] = kp[1]; kf.u[2] = kp[2]; kf.u[3] = kp[3];
            return kf.v;
        };

        // --- pipelined mc loop: scur holds QKT(mc), QKT(mc+1) issues before exp/PV(mc)
        f32x16 scur0, scur1;
        {
            const short8 kf = loadK(0);
            scur0 = __builtin_amdgcn_mfma_f32_32x32x16_bf16(kf, qf[0], z16, 0, 0, 0);
            scur1 = __builtin_amdgcn_mfma_f32_32x32x16_bf16(kf, qf[1], z16, 0, 0, 0);
        }
#pragma unroll
        for (int mc = 0; mc < 8; ++mc) {
            f32x16 snext0, snext1;
            if (mc < 7) {
                const short8 kf = loadK(mc + 1);
                snext0 = __builtin_amdgcn_mfma_f32_32x32x16_bf16(kf, qf[0], z16, 0, 0, 0);
                snext1 = __builtin_amdgcn_mfma_f32_32x32x16_bf16(kf, qf[1], z16, 0, 0, 0);
            }
            const int mb = mc << 5;
            union { short8 v; uint2v u2[2]; } vf1, vf2;
            vf1.u2[0] = *reinterpret_cast<const uint2v*>(&Vs[vrow][mb + hi * 4]);
            vf1.u2[1] = *reinterpret_cast<const uint2v*>(&Vs[vrow][mb + 8 + hi * 4]);
            vf2.u2[0] = *reinterpret_cast<const uint2v*>(&Vs[vrow][mb + 16 + hi * 4]);
            vf2.u2[1] = *reinterpret_cast<const uint2v*>(&Vs[vrow][mb + 24 + hi * 4]);
#pragma unroll
            for (int i = 0; i < 2; ++i) {
                const f32x16 s = (i == 0) ? scur0 : scur1;
                union { short8 v; unsigned int u[4]; } p1, p2;
#pragma unroll
                for (int r = 0; r < 4; ++r) {
                    p1.u[r] = cvt_pk_bf16(__builtin_amdgcn_exp2f(s[2 * r]),
                                          __builtin_amdgcn_exp2f(s[2 * r + 1]));
                    p2.u[r] = cvt_pk_bf16(__builtin_amdgcn_exp2f(s[8 + 2 * r]),
                                          __builtin_amdgcn_exp2f(s[8 + 2 * r + 1]));
                }
                acc[i] = __builtin_amdgcn_mfma_f32_32x32x16_bf16(p1.v, vf1.v, acc[i], 0, 0, 0);
                acc[i] = __builtin_amdgcn_mfma_f32_32x32x16_bf16(p2.v, vf2.v, acc[i], 0, 0, 0);
            }
            if (mc < 7) { scur0 = snext0; scur1 = snext1; }
        }
    }

    // inverse row-sums from the ones-column
    float invq[2][16];
#pragma unroll
    for (int i = 0; i < 2; ++i)
#pragma unroll
        for (int r = 0; r < 16; ++r)
            invq[i][r] = 1.0f / __shfl(acc[i][r], (lane & 32) | 12);

    __syncthreads();
#pragma unroll
    for (int i = 0; i < 2; ++i) {
        unsigned short* OtW = &Ks[0][0] + (i * 4 + w) * OT_STRIDE;
        if (q31 < HD) {
#pragma unroll
            for (int r2 = 0; r2 < 8; ++r2) {
                const int r = 2 * r2;
                const int q = (r & 3) + 8 * (r >> 2) + 4 * hi;
                const unsigned int dw = (unsigned int)f2bf(acc[i][r] * invq[i][r]) |
                                        ((unsigned int)f2bf(acc[i][r + 1] * invq[i][r + 1]) << 16);
                *reinterpret_cast<unsigned int*>(&OtW[q31 * 32 + q]) = dw;
            }
        }
    }
    __syncthreads();
    {
        const int q = t;
        const int obi = ((q >> 7) * 4) + ((q >> 5) & 3);
        const int ql = q & 31;
        const unsigned short* Osrc = &Ks[0][0] + obi * OT_STRIDE + ql;
        unsigned int dwv[6];
#pragma unroll
        for (int dp = 0; dp < 6; ++dp)
            dwv[dp] = (unsigned int)Osrc[(2 * dp) * 32] | ((unsigned int)Osrc[(2 * dp + 1) * 32] << 16);
        unsigned int* dst = reinterpret_cast<unsigned int*>(
            fused2 + ((size_t)b * HWN + n0 + q) * KTOT + coff + h * HD);
#pragma unroll
        for (int dp = 0; dp < 6; ++dp) dst[dp] = dwv[dp];
    }
}

extern "C" void kernel_launch(void* const* d_in, const int* in_sizes, int n_in,
                              void* d_out, int out_size, void* d_ws, size_t ws_size,
                              hipStream_t stream) {
    (void)in_sizes; (void)n_in; (void)out_size; (void)ws_size;
    const float* x   = (const float*)d_in[0];
    const float* xbp = (const float*)d_in[1];
    const float* Wq  = (const float*)d_in[2];  const float* bq  = (const float*)d_in[3];
    const float* Wk  = (const float*)d_in[4];  const float* bk  = (const float*)d_in[5];
    const float* Wv  = (const float*)d_in[6];  const float* bv  = (const float*)d_in[7];
    const float* Wqb = (const float*)d_in[8];  const float* bqb = (const float*)d_in[9];
    const float* Wkb = (const float*)d_in[10]; const float* bkb = (const float*)d_in[11];
    const float* Wvb = (const float*)d_in[12]; const float* bvb = (const float*)d_in[13];
    const float* Wo  = (const float*)d_in[14]; const float* bo  = (const float*)d_in[15];
    float* out = (float*)d_out;

    char* ws = (char*)d_ws;
    size_t off = 0;
    auto alloc = [&](size_t bytes) -> void* {
        void* p = ws + off;
        off = (off + bytes + 255) & ~(size_t)255;
        return p;
    };
    unsigned short* wbf[6];
    for (int i = 0; i < 6; ++i) wbf[i] = (unsigned short*)alloc((size_t)EMBED * EMBED * 2);
    unsigned short* wo2 = (unsigned short*)alloc((size_t)HIDDEN * KTOT * 2);
    unsigned short* qkv[6];
    for (int i = 0; i < 6; ++i) qkv[i] = (unsigned short*)alloc((size_t)BB * EMBED * HWN * 2);
    unsigned short* fused2 = (unsigned short*)alloc((size_t)BB * HWN * KTOT * 2);

    // 1) weights -> bf16 (Wo duplicated into Wo2)
    WConv wc;
    const float* wsrc[7] = {Wq, Wk, Wv, Wqb, Wkb, Wvb, Wo};
    unsigned short* wdst[7] = {wbf[0], wbf[1], wbf[2], wbf[3], wbf[4], wbf[5], wo2};
    int acc4 = 0;
    for (int i = 0; i < 7; ++i) {
        const int n = (i < 6) ? EMBED * EMBED : HIDDEN * 768;
        wc.src[i] = wsrc[i];
        wc.dst[i] = wdst[i];
        wc.start[i] = acc4;
        acc4 += n / 4;
    }
    wc.start[7] = acc4;
    k_bf16_all<<<(acc4 + 255) / 256, 256, 0, stream>>>(wc);

    // 2) x, x_bpf -> token-major bf16 into fused2 cols 768..1535
    k_transpose<<<dim3(EMBED / 32, HWN / 32, 16), 256, 0, stream>>>(x, xbp, fused2);

    // 3) six QKV projections (128x128 tiles)
    QkvTable tab;
    tab.W[0] = wbf[0]; tab.W[1] = wbf[1]; tab.W[2] = wbf[2];
    tab.W[3] = wbf[3]; tab.W[4] = wbf[4]; tab.W[5] = wbf[5];
    tab.bias[0] = bq; tab.bias[1] = bk; tab.bias[2] = bv;
    tab.bias[3] = bqb; tab.bias[4] = bkb; tab.bias[5] = bvb;
    tab.fused2 = fused2;
    for (int i = 0; i < 6; ++i) tab.out[i] = qkv[i];
    k_gemm_qkv<<<dim3(EMBED / 128, HWN / 128, BB * 6), 256, 0, stream>>>(tab);

    // 4) MFMA attention -> fused2 cols 0..767 (512 instances x 4 q-tiles of 256, XCD-local)
    k_attn_mfma<<<dim3(2048), 256, 0, stream>>>(qkv[0], qkv[1], qkv[2], qkv[3], qkv[4], qkv[5],
                                                fused2);

    // 5) out = Wo2 . fused2 + bo   (K=1536 folds the residual)
    k_gemm_out<<<dim3(HIDDEN / 128, HWN / 128, BB), 256, 0, stream>>>(wo2, fused2, bo, out);
}

// Round 21
// 166.929 us; speedup vs baseline: 1.0645x; 1.0645x over previous
//
#include <hip/hip_runtime.h>
#include <hip/hip_bf16.h>

#define BB 8
#define EMBED 384
#define NH 32
#define HD 12
#define HWN 1024
#define HIDDEN 512
#define KTOT 1536
#define SCALE 0.28867513459481287f

typedef __attribute__((ext_vector_type(8))) unsigned short ushort8;
typedef __attribute__((ext_vector_type(8))) short short8;
typedef __attribute__((ext_vector_type(4))) float f32x4;
typedef __attribute__((ext_vector_type(16))) float f32x16;
typedef __attribute__((ext_vector_type(4))) unsigned short ushort4v;
typedef __attribute__((ext_vector_type(2))) unsigned int uint2v;

static __device__ __forceinline__ float bf2f(unsigned short u) {
    return __uint_as_float(((unsigned int)u) << 16);
}
static __device__ __forceinline__ unsigned short f2bf(float f) {
    unsigned int u = __float_as_uint(f);
    u = u + 0x7FFFu + ((u >> 16) & 1u);   // RNE
    return (unsigned short)(u >> 16);
}
static __device__ __forceinline__ unsigned int cvt_pk_bf16(float lo, float hi) {
    unsigned int r;
    asm("v_cvt_pk_bf16_f32 %0, %1, %2" : "=v"(r) : "v"(lo), "v"(hi));
    return r;
}

#if __has_builtin(__builtin_amdgcn_global_load_lds)
#define HAVE_GLOAD_LDS 1
static __device__ __forceinline__ void gl_lds16(const unsigned short* g, unsigned short* l) {
    __builtin_amdgcn_global_load_lds(
        (const __attribute__((address_space(1))) unsigned int*)g,
        (__attribute__((address_space(3))) unsigned int*)l, 16, 0, 0);
}
#else
#define HAVE_GLOAD_LDS 0
#endif

// ---------------- f32 -> bf16 weights; Wo duplicated into Wo2[512][1536] ----------------
struct WConv {
    const float* src[7];
    unsigned short* dst[7];
    int start[8];   // prefix over vec4 counts
};

__global__ __launch_bounds__(256) void k_bf16_all(WConv wc) {
    int i = blockIdx.x * 256 + threadIdx.x;
    if (i >= wc.start[7]) return;
    int p = 0;
#pragma unroll
    for (int j = 1; j < 7; ++j) p += (i >= wc.start[j]);
    const int e = i - wc.start[p];
    const f32x4 v = reinterpret_cast<const f32x4*>(wc.src[p])[e];
    ushort4v o;
#pragma unroll
    for (int j = 0; j < 4; ++j) o[j] = f2bf(v[j]);
    if (p == 6) {
        const int row = e / 192, cc = e % 192;
        ushort4v* d = reinterpret_cast<ushort4v*>(wc.dst[6]);
        d[row * 384 + cc] = o;
        d[row * 384 + 192 + cc] = o;
    } else {
        reinterpret_cast<ushort4v*>(wc.dst[p])[e] = o;
    }
}

// ---------------- transpose x (B,C,HW) f32 -> fused2[b][n][768 + s*384 + c] bf16 ----------------
__global__ __launch_bounds__(256) void k_transpose(const float* __restrict__ x0, const float* __restrict__ x1,
                                                   unsigned short* __restrict__ fused2) {
    __shared__ float tile[32][33];
    const int z = blockIdx.z;
    const int s = z >> 3, b = z & 7;
    const float* src = (s ? x1 : x0) + (size_t)b * EMBED * HWN;
    unsigned short* dst = fused2 + (size_t)b * HWN * KTOT + 768 + s * 384;
    const int c0 = blockIdx.x * 32;
    const int n0 = blockIdx.y * 32;
    const int tc = threadIdx.x & 31;
    const int tr = threadIdx.x >> 5;
#pragma unroll
    for (int p = 0; p < 4; ++p) {
        int r = tr + p * 8;
        tile[r][tc] = src[(size_t)(c0 + r) * HWN + n0 + tc];
    }
    __syncthreads();
#pragma unroll
    for (int p = 0; p < 4; ++p) {
        int r = tr + p * 8;
        dst[(size_t)(n0 + r) * KTOT + c0 + tc] = f2bf(tile[tc][r]);
    }
}

// ---------------- bf16 MFMA GEMM 128x128xBK64 (m97 structure) ----------------
template <bool F32OUT>
static __device__ __forceinline__ void gemm128(const unsigned short* __restrict__ A, int lda,
                                               const unsigned short* __restrict__ Bt, int ldb,
                                               const float* __restrict__ bias,
                                               unsigned short* __restrict__ outBf,
                                               float* __restrict__ outF,
                                               int K, int bx, int by) {
    __shared__ unsigned short As[128][64];
    __shared__ unsigned short Bs[128][64];
    const int t = threadIdx.x;
    const int lane = t & 63;
    const int w = t >> 6;
    const int wr = w >> 1, wc = w & 1;
    const int o0 = bx * 128, n0 = by * 128;
    const int srow = lane >> 3;
    const int scol = (lane & 7) * 8;

    f32x4 acc[4][4] = {};

    for (int k0 = 0; k0 < K; k0 += 64) {
#pragma unroll
        for (int i = 0; i < 4; ++i) {
            const int c = w * 4 + i;
            const int r = c * 8 + srow;
#if HAVE_GLOAD_LDS
            gl_lds16(A + (size_t)(o0 + r) * lda + k0 + scol, &As[c * 8][0]);
            gl_lds16(Bt + (size_t)(n0 + r) * ldb + k0 + scol, &Bs[c * 8][0]);
#else
            *reinterpret_cast<ushort8*>(&As[r][scol]) =
                *reinterpret_cast<const ushort8*>(A + (size_t)(o0 + r) * lda + k0 + scol);
            *reinterpret_cast<ushort8*>(&Bs[r][scol]) =
                *reinterpret_cast<const ushort8*>(Bt + (size_t)(n0 + r) * ldb + k0 + scol);
#endif
        }
        __syncthreads();
#pragma unroll
        for (int kk = 0; kk < 2; ++kk) {
            const int ko = kk * 32 + ((lane >> 4) << 3);
            short8 af[4], bf[4];
#pragma unroll
            for (int i = 0; i < 4; ++i) {
                af[i] = *reinterpret_cast<const short8*>(&As[wr * 64 + i * 16 + (lane & 15)][ko]);
                bf[i] = *reinterpret_cast<const short8*>(&Bs[wc * 64 + i * 16 + (lane & 15)][ko]);
            }
#pragma unroll
            for (int i = 0; i < 4; ++i)
#pragma unroll
                for (int j = 0; j < 4; ++j)
                    acc[i][j] = __builtin_amdgcn_mfma_f32_16x16x32_bf16(af[i], bf[j], acc[i][j], 0, 0, 0);
        }
        __syncthreads();
    }
#pragma unroll
    for (int i = 0; i < 4; ++i) {
#pragma unroll
        for (int j = 0; j < 4; ++j) {
            const int ob = o0 + wr * 64 + i * 16 + ((lane >> 4) << 2);
            const int n  = n0 + wc * 64 + j * 16 + (lane & 15);
#pragma unroll
            for (int r = 0; r < 4; ++r) {
                const int o = ob + r;
                float v = acc[i][j][r] + bias[o];
                if constexpr (F32OUT) outF[(size_t)o * HWN + n] = v;
                else                  outBf[(size_t)o * HWN + n] = f2bf(v);
            }
        }
    }
}

struct QkvTable {
    const unsigned short* W[6];
    const float* bias[6];
    const unsigned short* fused2;
    unsigned short* out[6];
};

__global__ __launch_bounds__(256) void k_gemm_qkv(QkvTable tab) {
    const int z = blockIdx.z;
    const int b = z / 6, p = z % 6;
    const unsigned short* Bt = tab.fused2 + (size_t)b * HWN * KTOT + 768 + (p / 3) * 384;
    gemm128<false>(tab.W[p], EMBED, Bt, KTOT, tab.bias[p],
                   tab.out[p] + (size_t)b * EMBED * HWN, nullptr,
                   EMBED, blockIdx.x, blockIdx.y);
}

__global__ __launch_bounds__(256) void k_gemm_out(const unsigned short* __restrict__ Wo2,
                                                  const unsigned short* __restrict__ fused2,
                                                  const float* __restrict__ bo,
                                                  float* __restrict__ out) {
    const int b = blockIdx.z;
    gemm128<true>(Wo2, KTOT, fused2 + (size_t)b * HWN * KTOT, KTOT, bo,
                  nullptr, out + (size_t)b * HIDDEN * HWN,
                  KTOT, blockIdx.x, blockIdx.y);
}

// ---------------- MFMA flash attention v8 (round-19 verified): 32x32x16 register-P, 4 phases ----------------
#define OT_STRIDE 416
__global__ __launch_bounds__(256) void k_attn_mfma(const unsigned short* __restrict__ qc,
                                                   const unsigned short* __restrict__ kc,
                                                   const unsigned short* __restrict__ vc,
                                                   const unsigned short* __restrict__ qcb,
                                                   const unsigned short* __restrict__ kcb,
                                                   const unsigned short* __restrict__ vcb,
                                                   unsigned short* __restrict__ fused2) {
    __shared__ unsigned short Ks[256][18];   // [m][d 0..15 + 2 pad], 36B rows (9 dw, coprime 32)
    __shared__ unsigned short Vs[13][264];   // [d][m], row 12 = ones

    const int bid = blockIdx.x;
    const int inst = bid & 511, qt = bid >> 9;
    const int branch = inst >> 8, b = (inst >> 5) & 7, h = inst & 31;
    const unsigned short* Qg = branch ? qc : qcb;
    const unsigned short* Kg = branch ? kcb : kc;
    const unsigned short* Vg = branch ? vcb : vc;
    const int coff = branch ? 384 : 0;
    const size_t base = ((size_t)b * EMBED + h * HD) * HWN;
    const int t = threadIdx.x;
    const int lane = t & 63, w = t >> 6;
    const int q31 = lane & 31, hi = lane >> 5;
    const int n0 = qt * 256;
    const float C2 = SCALE * 1.4426950408889634f;

    // Q B-frags (32x32x16): frag i -> q = n0 + i*128 + w*32 + q31, pre-scaled by C2
    short8 qf[2] = {};
#pragma unroll
    for (int i = 0; i < 2; ++i) {
        const int qg = n0 + i * 128 + w * 32 + q31;
#pragma unroll
        for (int j = 0; j < 8; ++j) {
            const int d = hi * 8 + j;
            if (d < HD)
                qf[i][j] = (short)f2bf(bf2f(Qg[base + (size_t)d * HWN + qg]) * C2);
        }
    }

    f32x16 acc[2], z16;
#pragma unroll
    for (int r = 0; r < 16; ++r) { acc[0][r] = 0.f; acc[1][r] = 0.f; z16[r] = 0.f; }
    const int vrow = (q31 < HD) ? q31 : 12;   // lanes d>=12 read ones row (outputs discarded)

    for (int phase = 0; phase < 4; ++phase) {
        const int m0 = phase << 8;
        __syncthreads();   // prior-phase reads done
        // --- stage K (256 m): wave w owns d-rows 4w..4w+3 (w=3 -> zeros). 128B-coalesced gathers.
        {
            const size_t kb = base + (size_t)(4 * w) * HWN + m0;
#pragma unroll
            for (int it = 0; it < 4; ++it) {
                const int m = it * 64 + lane;
                unsigned int da = 0, db = 0;
                if (w < 3) {
                    da = (unsigned int)Kg[kb + m] | ((unsigned int)Kg[kb + HWN + m] << 16);
                    db = (unsigned int)Kg[kb + 2 * HWN + m] | ((unsigned int)Kg[kb + 3 * HWN + m] << 16);
                }
                unsigned int* p = reinterpret_cast<unsigned int*>(&Ks[m][w * 4]);
                p[0] = da;
                p[1] = db;
            }
        }
        // --- stage V (256 m): wave w<3 owns d-rows 4w..4w+3; w==3 lanes<32 write ones row (d=12)
        if (w < 3) {
#pragma unroll
            for (int r2 = 0; r2 < 2; ++r2) {
                const int d = 4 * w + 2 * r2 + (lane >> 5);
                const int col = (lane & 31) * 8;
                *reinterpret_cast<ushort8*>(&Vs[d][col]) =
                    *reinterpret_cast<const ushort8*>(&Vg[base + (size_t)d * HWN + m0 + col]);
            }
        } else if (lane < 32) {
            ushort8 ones;
#pragma unroll
            for (int j = 0; j < 8; ++j) ones[j] = 0x3F80;
            *reinterpret_cast<ushort8*>(&Vs[12][lane * 8]) = ones;
        }
        __syncthreads();

        for (int mc = 0; mc < 8; ++mc) {
            const int mb = mc << 5;
            // K A-frag: lane (m-local = q31, hi) = K[mb+q31][d = hi*8+j]; dword loads (36B rows)
            union { short8 v; unsigned int u[4]; } kf;
            {
                const unsigned int* kp = reinterpret_cast<const unsigned int*>(&Ks[mb + q31][hi * 8]);
                kf.u[0] = kp[0]; kf.u[1] = kp[1]; kf.u[2] = kp[2]; kf.u[3] = kp[3];
            }
            // V B-frags, sigma-permuted k-rows: PV1 m {0..3,8..11}+4hi, PV2 +16
            union { short8 v; uint2v u2[2]; } vf1, vf2;
            vf1.u2[0] = *reinterpret_cast<const uint2v*>(&Vs[vrow][mb + hi * 4]);
            vf1.u2[1] = *reinterpret_cast<const uint2v*>(&Vs[vrow][mb + 8 + hi * 4]);
            vf2.u2[0] = *reinterpret_cast<const uint2v*>(&Vs[vrow][mb + 16 + hi * 4]);
            vf2.u2[1] = *reinterpret_cast<const uint2v*>(&Vs[vrow][mb + 24 + hi * 4]);
#pragma unroll
            for (int i = 0; i < 2; ++i) {
                // QKT: C reg r = P[m=(r&3)+8*(r>>2)+4hi][q=q31]
                const f32x16 s = __builtin_amdgcn_mfma_f32_32x32x16_bf16(kf.v, qf[i], z16, 0, 0, 0);
                union { short8 v; unsigned int u[4]; } p1, p2;
#pragma unroll
                for (int r = 0; r < 4; ++r) {
                    p1.u[r] = cvt_pk_bf16(__builtin_amdgcn_exp2f(s[2 * r]),
                                          __builtin_amdgcn_exp2f(s[2 * r + 1]));
                    p2.u[r] = cvt_pk_bf16(__builtin_amdgcn_exp2f(s[8 + 2 * r]),
                                          __builtin_amdgcn_exp2f(s[8 + 2 * r + 1]));
                }
                acc[i] = __builtin_amdgcn_mfma_f32_32x32x16_bf16(p1.v, vf1.v, acc[i], 0, 0, 0);
                acc[i] = __builtin_amdgcn_mfma_f32_32x32x16_bf16(p2.v, vf2.v, acc[i], 0, 0, 0);
            }
        }
    }

    // inverse row-sums: output col 12 (ones row) at lane (lane&32)|12, same reg
    float invq[2][16];
#pragma unroll
    for (int i = 0; i < 2; ++i)
#pragma unroll
        for (int r = 0; r < 16; ++r)
            invq[i][r] = 1.0f / __shfl(acc[i][r], (lane & 32) | 12);

    __syncthreads();   // all Ks/Vs reads done before Ot overwrites Ks
#pragma unroll
    for (int i = 0; i < 2; ++i) {
        unsigned short* OtW = &Ks[0][0] + (i * 4 + w) * OT_STRIDE;
        if (q31 < HD) {
#pragma unroll
            for (int r2 = 0; r2 < 8; ++r2) {
                const int r = 2 * r2;
                const int q = (r & 3) + 8 * (r >> 2) + 4 * hi;
                const unsigned int dw = (unsigned int)f2bf(acc[i][r] * invq[i][r]) |
                                        ((unsigned int)f2bf(acc[i][r + 1] * invq[i][r + 1]) << 16);
                *reinterpret_cast<unsigned int*>(&OtW[q31 * 32 + q]) = dw;
            }
        }
    }
    __syncthreads();
    {
        const int q = t;
        const int obi = ((q >> 7) * 4) + ((q >> 5) & 3);
        const int ql = q & 31;
        const unsigned short* Osrc = &Ks[0][0] + obi * OT_STRIDE + ql;
        unsigned int dwv[6];
#pragma unroll
        for (int dp = 0; dp < 6; ++dp)
            dwv[dp] = (unsigned int)Osrc[(2 * dp) * 32] | ((unsigned int)Osrc[(2 * dp + 1) * 32] << 16);
        unsigned int* dst = reinterpret_cast<unsigned int*>(
            fused2 + ((size_t)b * HWN + n0 + q) * KTOT + coff + h * HD);
#pragma unroll
        for (int dp = 0; dp < 6; ++dp) dst[dp] = dwv[dp];
    }
}

extern "C" void kernel_launch(void* const* d_in, const int* in_sizes, int n_in,
                              void* d_out, int out_size, void* d_ws, size_t ws_size,
                              hipStream_t stream) {
    (void)in_sizes; (void)n_in; (void)out_size; (void)ws_size;
    const float* x   = (const float*)d_in[0];
    const float* xbp = (const float*)d_in[1];
    const float* Wq  = (const float*)d_in[2];  const float* bq  = (const float*)d_in[3];
    const float* Wk  = (const float*)d_in[4];  const float* bk  = (const float*)d_in[5];
    const float* Wv  = (const float*)d_in[6];  const float* bv  = (const float*)d_in[7];
    const float* Wqb = (const float*)d_in[8];  const float* bqb = (const float*)d_in[9];
    const float* Wkb = (const float*)d_in[10]; const float* bkb = (const float*)d_in[11];
    const float* Wvb = (const float*)d_in[12]; const float* bvb = (const float*)d_in[13];
    const float* Wo  = (const float*)d_in[14]; const float* bo  = (const float*)d_in[15];
    float* out = (float*)d_out;

    char* ws = (char*)d_ws;
    size_t off = 0;
    auto alloc = [&](size_t bytes) -> void* {
        void* p = ws + off;
        off = (off + bytes + 255) & ~(size_t)255;
        return p;
    };
    unsigned short* wbf[6];
    for (int i = 0; i < 6; ++i) wbf[i] = (unsigned short*)alloc((size_t)EMBED * EMBED * 2);
    unsigned short* wo2 = (unsigned short*)alloc((size_t)HIDDEN * KTOT * 2);
    unsigned short* qkv[6];
    for (int i = 0; i < 6; ++i) qkv[i] = (unsigned short*)alloc((size_t)BB * EMBED * HWN * 2);
    unsigned short* fused2 = (unsigned short*)alloc((size_t)BB * HWN * KTOT * 2);

    // 1) weights -> bf16 (Wo duplicated into Wo2)
    WConv wc;
    const float* wsrc[7] = {Wq, Wk, Wv, Wqb, Wkb, Wvb, Wo};
    unsigned short* wdst[7] = {wbf[0], wbf[1], wbf[2], wbf[3], wbf[4], wbf[5], wo2};
    int acc4 = 0;
    for (int i = 0; i < 7; ++i) {
        const int n = (i < 6) ? EMBED * EMBED : HIDDEN * 768;
        wc.src[i] = wsrc[i];
        wc.dst[i] = wdst[i];
        wc.start[i] = acc4;
        acc4 += n / 4;
    }
    wc.start[7] = acc4;
    k_bf16_all<<<(acc4 + 255) / 256, 256, 0, stream>>>(wc);

    // 2) x, x_bpf -> token-major bf16 into fused2 cols 768..1535
    k_transpose<<<dim3(EMBED / 32, HWN / 32, 16), 256, 0, stream>>>(x, xbp, fused2);

    // 3) six QKV projections (128x128 tiles)
    QkvTable tab;
    tab.W[0] = wbf[0]; tab.W[1] = wbf[1]; tab.W[2] = wbf[2];
    tab.W[3] = wbf[3]; tab.W[4] = wbf[4]; tab.W[5] = wbf[5];
    tab.bias[0] = bq; tab.bias[1] = bk; tab.bias[2] = bv;
    tab.bias[3] = bqb; tab.bias[4] = bkb; tab.bias[5] = bvb;
    tab.fused2 = fused2;
    for (int i = 0; i < 6; ++i) tab.out[i] = qkv[i];
    k_gemm_qkv<<<dim3(EMBED / 128, HWN / 128, BB * 6), 256, 0, stream>>>(tab);

    // 4) MFMA attention -> fused2 cols 0..767 (512 instances x 4 q-tiles of 256, XCD-local)
    k_attn_mfma<<<dim3(2048), 256, 0, stream>>>(qkv[0], qkv[1], qkv[2], qkv[3], qkv[4], qkv[5],
                                                fused2);

    // 5) out = Wo2 . fused2 + bo   (K=1536 folds the residual)
    k_gemm_out<<<dim3(HIDDEN / 128, HWN / 128, BB), 256, 0, stream>>>(wo2, fused2, bo, out);
}

// Round 22
// 165.813 us; speedup vs baseline: 1.0717x; 1.0067x over previous
//
#include <hip/hip_runtime.h>
#include <hip/hip_bf16.h>

#define BB 8
#define EMBED 384
#define NH 32
#define HD 12
#define HWN 1024
#define HIDDEN 512
#define KTOT 1536
#define SCALE 0.28867513459481287f

typedef __attribute__((ext_vector_type(8))) unsigned short ushort8;
typedef __attribute__((ext_vector_type(8))) short short8;
typedef __attribute__((ext_vector_type(4))) float f32x4;
typedef __attribute__((ext_vector_type(16))) float f32x16;
typedef __attribute__((ext_vector_type(4))) unsigned short ushort4v;
typedef __attribute__((ext_vector_type(2))) unsigned int uint2v;

static __device__ __forceinline__ float bf2f(unsigned short u) {
    return __uint_as_float(((unsigned int)u) << 16);
}
static __device__ __forceinline__ unsigned short f2bf(float f) {
    unsigned int u = __float_as_uint(f);
    u = u + 0x7FFFu + ((u >> 16) & 1u);   // RNE
    return (unsigned short)(u >> 16);
}
static __device__ __forceinline__ unsigned int cvt_pk_bf16(float lo, float hi) {
    unsigned int r;
    asm("v_cvt_pk_bf16_f32 %0, %1, %2" : "=v"(r) : "v"(lo), "v"(hi));
    return r;
}

#if __has_builtin(__builtin_amdgcn_global_load_lds)
#define HAVE_GLOAD_LDS 1
static __device__ __forceinline__ void gl_lds16(const unsigned short* g, unsigned short* l) {
    __builtin_amdgcn_global_load_lds(
        (const __attribute__((address_space(1))) unsigned int*)g,
        (__attribute__((address_space(3))) unsigned int*)l, 16, 0, 0);
}
#else
#define HAVE_GLOAD_LDS 0
#endif

// ---------------- f32 -> bf16 weights; Wo duplicated into Wo2[512][1536] ----------------
struct WConv {
    const float* src[7];
    unsigned short* dst[7];
    int start[8];   // prefix over vec4 counts
};

__global__ __launch_bounds__(256) void k_bf16_all(WConv wc) {
    int i = blockIdx.x * 256 + threadIdx.x;
    if (i >= wc.start[7]) return;
    int p = 0;
#pragma unroll
    for (int j = 1; j < 7; ++j) p += (i >= wc.start[j]);
    const int e = i - wc.start[p];
    const f32x4 v = reinterpret_cast<const f32x4*>(wc.src[p])[e];
    ushort4v o;
#pragma unroll
    for (int j = 0; j < 4; ++j) o[j] = f2bf(v[j]);
    if (p == 6) {
        const int row = e / 192, cc = e % 192;
        ushort4v* d = reinterpret_cast<ushort4v*>(wc.dst[6]);
        d[row * 384 + cc] = o;
        d[row * 384 + 192 + cc] = o;
    } else {
        reinterpret_cast<ushort4v*>(wc.dst[p])[e] = o;
    }
}

// ---------------- transpose x (B,C,HW) f32 -> fused2[b][n][768 + s*384 + c] bf16 ----------------
__global__ __launch_bounds__(256) void k_transpose(const float* __restrict__ x0, const float* __restrict__ x1,
                                                   unsigned short* __restrict__ fused2) {
    __shared__ float tile[32][33];
    const int z = blockIdx.z;
    const int s = z >> 3, b = z & 7;
    const float* src = (s ? x1 : x0) + (size_t)b * EMBED * HWN;
    unsigned short* dst = fused2 + (size_t)b * HWN * KTOT + 768 + s * 384;
    const int c0 = blockIdx.x * 32;
    const int n0 = blockIdx.y * 32;
    const int tc = threadIdx.x & 31;
    const int tr = threadIdx.x >> 5;
#pragma unroll
    for (int p = 0; p < 4; ++p) {
        int r = tr + p * 8;
        tile[r][tc] = src[(size_t)(c0 + r) * HWN + n0 + tc];
    }
    __syncthreads();
#pragma unroll
    for (int p = 0; p < 4; ++p) {
        int r = tr + p * 8;
        dst[(size_t)(n0 + r) * KTOT + c0 + tc] = f2bf(tile[tc][r]);
    }
}

// ---------------- bf16 MFMA GEMM 128x128xBK64 (m97 structure) ----------------
template <bool F32OUT>
static __device__ __forceinline__ void gemm128(const unsigned short* __restrict__ A, int lda,
                                               const unsigned short* __restrict__ Bt, int ldb,
                                               const float* __restrict__ bias,
                                               unsigned short* __restrict__ outBf,
                                               float* __restrict__ outF,
                                               int K, int bx, int by) {
    __shared__ unsigned short As[128][64];
    __shared__ unsigned short Bs[128][64];
    const int t = threadIdx.x;
    const int lane = t & 63;
    const int w = t >> 6;
    const int wr = w >> 1, wc = w & 1;
    const int o0 = bx * 128, n0 = by * 128;
    const int srow = lane >> 3;
    const int scol = (lane & 7) * 8;

    f32x4 acc[4][4] = {};

    for (int k0 = 0; k0 < K; k0 += 64) {
#pragma unroll
        for (int i = 0; i < 4; ++i) {
            const int c = w * 4 + i;
            const int r = c * 8 + srow;
#if HAVE_GLOAD_LDS
            gl_lds16(A + (size_t)(o0 + r) * lda + k0 + scol, &As[c * 8][0]);
            gl_lds16(Bt + (size_t)(n0 + r) * ldb + k0 + scol, &Bs[c * 8][0]);
#else
            *reinterpret_cast<ushort8*>(&As[r][scol]) =
                *reinterpret_cast<const ushort8*>(A + (size_t)(o0 + r) * lda + k0 + scol);
            *reinterpret_cast<ushort8*>(&Bs[r][scol]) =
                *reinterpret_cast<const ushort8*>(Bt + (size_t)(n0 + r) * ldb + k0 + scol);
#endif
        }
        __syncthreads();
#pragma unroll
        for (int kk = 0; kk < 2; ++kk) {
            const int ko = kk * 32 + ((lane >> 4) << 3);
            short8 af[4], bf[4];
#pragma unroll
            for (int i = 0; i < 4; ++i) {
                af[i] = *reinterpret_cast<const short8*>(&As[wr * 64 + i * 16 + (lane & 15)][ko]);
                bf[i] = *reinterpret_cast<const short8*>(&Bs[wc * 64 + i * 16 + (lane & 15)][ko]);
            }
#pragma unroll
            for (int i = 0; i < 4; ++i)
#pragma unroll
                for (int j = 0; j < 4; ++j)
                    acc[i][j] = __builtin_amdgcn_mfma_f32_16x16x32_bf16(af[i], bf[j], acc[i][j], 0, 0, 0);
        }
        __syncthreads();
    }
#pragma unroll
    for (int i = 0; i < 4; ++i) {
#pragma unroll
        for (int j = 0; j < 4; ++j) {
            const int ob = o0 + wr * 64 + i * 16 + ((lane >> 4) << 2);
            const int n  = n0 + wc * 64 + j * 16 + (lane & 15);
#pragma unroll
            for (int r = 0; r < 4; ++r) {
                const int o = ob + r;
                float v = acc[i][j][r] + bias[o];
                if constexpr (F32OUT) outF[(size_t)o * HWN + n] = v;
                else                  outBf[(size_t)o * HWN + n] = f2bf(v);
            }
        }
    }
}

struct QkvTable {
    const unsigned short* W[6];
    const float* bias[6];
    const unsigned short* fused2;
    unsigned short* out[6];
};

__global__ __launch_bounds__(256) void k_gemm_qkv(QkvTable tab) {
    const int z = blockIdx.z;
    const int b = z / 6, p = z % 6;
    const unsigned short* Bt = tab.fused2 + (size_t)b * HWN * KTOT + 768 + (p / 3) * 384;
    gemm128<false>(tab.W[p], EMBED, Bt, KTOT, tab.bias[p],
                   tab.out[p] + (size_t)b * EMBED * HWN, nullptr,
                   EMBED, blockIdx.x, blockIdx.y);
}

__global__ __launch_bounds__(256) void k_gemm_out(const unsigned short* __restrict__ Wo2,
                                                  const unsigned short* __restrict__ fused2,
                                                  const float* __restrict__ bo,
                                                  float* __restrict__ out) {
    const int b = blockIdx.z;
    gemm128<true>(Wo2, KTOT, fused2 + (size_t)b * HWN * KTOT, KTOT, bo,
                  nullptr, out + (size_t)b * HIDDEN * HWN,
                  KTOT, blockIdx.x, blockIdx.y);
}

// ---------------- MFMA flash attention v8.1: round-19 structure + s_setprio around MFMA cluster ----------------
// T5 (m191): priority boost on the MFMA/exp burst pays when co-resident blocks are at different
// phases (independent, not barrier-locked across blocks) -- attn's regime, not the GEMMs'.
#define OT_STRIDE 416
__global__ __launch_bounds__(256) void k_attn_mfma(const unsigned short* __restrict__ qc,
                                                   const unsigned short* __restrict__ kc,
                                                   const unsigned short* __restrict__ vc,
                                                   const unsigned short* __restrict__ qcb,
                                                   const unsigned short* __restrict__ kcb,
                                                   const unsigned short* __restrict__ vcb,
                                                   unsigned short* __restrict__ fused2) {
    __shared__ unsigned short Ks[256][18];   // [m][d 0..15 + 2 pad], 36B rows (9 dw, coprime 32)
    __shared__ unsigned short Vs[13][264];   // [d][m], row 12 = ones

    const int bid = blockIdx.x;
    const int inst = bid & 511, qt = bid >> 9;
    const int branch = inst >> 8, b = (inst >> 5) & 7, h = inst & 31;
    const unsigned short* Qg = branch ? qc : qcb;
    const unsigned short* Kg = branch ? kcb : kc;
    const unsigned short* Vg = branch ? vcb : vc;
    const int coff = branch ? 384 : 0;
    const size_t base = ((size_t)b * EMBED + h * HD) * HWN;
    const int t = threadIdx.x;
    const int lane = t & 63, w = t >> 6;
    const int q31 = lane & 31, hi = lane >> 5;
    const int n0 = qt * 256;
    const float C2 = SCALE * 1.4426950408889634f;

    // Q B-frags (32x32x16): frag i -> q = n0 + i*128 + w*32 + q31, pre-scaled by C2
    short8 qf[2] = {};
#pragma unroll
    for (int i = 0; i < 2; ++i) {
        const int qg = n0 + i * 128 + w * 32 + q31;
#pragma unroll
        for (int j = 0; j < 8; ++j) {
            const int d = hi * 8 + j;
            if (d < HD)
                qf[i][j] = (short)f2bf(bf2f(Qg[base + (size_t)d * HWN + qg]) * C2);
        }
    }

    f32x16 acc[2], z16;
#pragma unroll
    for (int r = 0; r < 16; ++r) { acc[0][r] = 0.f; acc[1][r] = 0.f; z16[r] = 0.f; }
    const int vrow = (q31 < HD) ? q31 : 12;   // lanes d>=12 read ones row (outputs discarded)

    for (int phase = 0; phase < 4; ++phase) {
        const int m0 = phase << 8;
        __syncthreads();   // prior-phase reads done
        // --- stage K (256 m): wave w owns d-rows 4w..4w+3 (w=3 -> zeros). 128B-coalesced gathers.
        {
            const size_t kb = base + (size_t)(4 * w) * HWN + m0;
#pragma unroll
            for (int it = 0; it < 4; ++it) {
                const int m = it * 64 + lane;
                unsigned int da = 0, db = 0;
                if (w < 3) {
                    da = (unsigned int)Kg[kb + m] | ((unsigned int)Kg[kb + HWN + m] << 16);
                    db = (unsigned int)Kg[kb + 2 * HWN + m] | ((unsigned int)Kg[kb + 3 * HWN + m] << 16);
                }
                unsigned int* p = reinterpret_cast<unsigned int*>(&Ks[m][w * 4]);
                p[0] = da;
                p[1] = db;
            }
        }
        // --- stage V (256 m): wave w<3 owns d-rows 4w..4w+3; w==3 lanes<32 write ones row (d=12)
        if (w < 3) {
#pragma unroll
            for (int r2 = 0; r2 < 2; ++r2) {
                const int d = 4 * w + 2 * r2 + (lane >> 5);
                const int col = (lane & 31) * 8;
                *reinterpret_cast<ushort8*>(&Vs[d][col]) =
                    *reinterpret_cast<const ushort8*>(&Vg[base + (size_t)d * HWN + m0 + col]);
            }
        } else if (lane < 32) {
            ushort8 ones;
#pragma unroll
            for (int j = 0; j < 8; ++j) ones[j] = 0x3F80;
            *reinterpret_cast<ushort8*>(&Vs[12][lane * 8]) = ones;
        }
        __syncthreads();

        __builtin_amdgcn_s_setprio(1);
        for (int mc = 0; mc < 8; ++mc) {
            const int mb = mc << 5;
            // K A-frag: lane (m-local = q31, hi) = K[mb+q31][d = hi*8+j]; dword loads (36B rows)
            union { short8 v; unsigned int u[4]; } kf;
            {
                const unsigned int* kp = reinterpret_cast<const unsigned int*>(&Ks[mb + q31][hi * 8]);
                kf.u[0] = kp[0]; kf.u[1] = kp[1]; kf.u[2] = kp[2]; kf.u[3] = kp[3];
            }
            // V B-frags, sigma-permuted k-rows: PV1 m {0..3,8..11}+4hi, PV2 +16
            union { short8 v; uint2v u2[2]; } vf1, vf2;
            vf1.u2[0] = *reinterpret_cast<const uint2v*>(&Vs[vrow][mb + hi * 4]);
            vf1.u2[1] = *reinterpret_cast<const uint2v*>(&Vs[vrow][mb + 8 + hi * 4]);
            vf2.u2[0] = *reinterpret_cast<const uint2v*>(&Vs[vrow][mb + 16 + hi * 4]);
            vf2.u2[1] = *reinterpret_cast<const uint2v*>(&Vs[vrow][mb + 24 + hi * 4]);
#pragma unroll
            for (int i = 0; i < 2; ++i) {
                // QKT: C reg r = P[m=(r&3)+8*(r>>2)+4hi][q=q31]
                const f32x16 s = __builtin_amdgcn_mfma_f32_32x32x16_bf16(kf.v, qf[i], z16, 0, 0, 0);
                union { short8 v; unsigned int u[4]; } p1, p2;
#pragma unroll
                for (int r = 0; r < 4; ++r) {
                    p1.u[r] = cvt_pk_bf16(__builtin_amdgcn_exp2f(s[2 * r]),
                                          __builtin_amdgcn_exp2f(s[2 * r + 1]));
                    p2.u[r] = cvt_pk_bf16(__builtin_amdgcn_exp2f(s[8 + 2 * r]),
                                          __builtin_amdgcn_exp2f(s[8 + 2 * r + 1]));
                }
                acc[i] = __builtin_amdgcn_mfma_f32_32x32x16_bf16(p1.v, vf1.v, acc[i], 0, 0, 0);
                acc[i] = __builtin_amdgcn_mfma_f32_32x32x16_bf16(p2.v, vf2.v, acc[i], 0, 0, 0);
            }
        }
        __builtin_amdgcn_s_setprio(0);
    }

    // inverse row-sums: output col 12 (ones row) at lane (lane&32)|12, same reg
    float invq[2][16];
#pragma unroll
    for (int i = 0; i < 2; ++i)
#pragma unroll
        for (int r = 0; r < 16; ++r)
            invq[i][r] = 1.0f / __shfl(acc[i][r], (lane & 32) | 12);

    __syncthreads();   // all Ks/Vs reads done before Ot overwrites Ks
#pragma unroll
    for (int i = 0; i < 2; ++i) {
        unsigned short* OtW = &Ks[0][0] + (i * 4 + w) * OT_STRIDE;
        if (q31 < HD) {
#pragma unroll
            for (int r2 = 0; r2 < 8; ++r2) {
                const int r = 2 * r2;
                const int q = (r & 3) + 8 * (r >> 2) + 4 * hi;
                const unsigned int dw = (unsigned int)f2bf(acc[i][r] * invq[i][r]) |
                                        ((unsigned int)f2bf(acc[i][r + 1] * invq[i][r + 1]) << 16);
                *reinterpret_cast<unsigned int*>(&OtW[q31 * 32 + q]) = dw;
            }
        }
    }
    __syncthreads();
    {
        const int q = t;
        const int obi = ((q >> 7) * 4) + ((q >> 5) & 3);
        const int ql = q & 31;
        const unsigned short* Osrc = &Ks[0][0] + obi * OT_STRIDE + ql;
        unsigned int dwv[6];
#pragma unroll
        for (int dp = 0; dp < 6; ++dp)
            dwv[dp] = (unsigned int)Osrc[(2 * dp) * 32] | ((unsigned int)Osrc[(2 * dp + 1) * 32] << 16);
        unsigned int* dst = reinterpret_cast<unsigned int*>(
            fused2 + ((size_t)b * HWN + n0 + q) * KTOT + coff + h * HD);
#pragma unroll
        for (int dp = 0; dp < 6; ++dp) dst[dp] = dwv[dp];
    }
}

extern "C" void kernel_launch(void* const* d_in, const int* in_sizes, int n_in,
                              void* d_out, int out_size, void* d_ws, size_t ws_size,
                              hipStream_t stream) {
    (void)in_sizes; (void)n_in; (void)out_size; (void)ws_size;
    const float* x   = (const float*)d_in[0];
    const float* xbp = (const float*)d_in[1];
    const float* Wq  = (const float*)d_in[2];  const float* bq  = (const float*)d_in[3];
    const float* Wk  = (const float*)d_in[4];  const float* bk  = (const float*)d_in[5];
    const float* Wv  = (const float*)d_in[6];  const float* bv  = (const float*)d_in[7];
    const float* Wqb = (const float*)d_in[8];  const float* bqb = (const float*)d_in[9];
    const float* Wkb = (const float*)d_in[10]; const float* bkb = (const float*)d_in[11];
    const float* Wvb = (const float*)d_in[12]; const float* bvb = (const float*)d_in[13];
    const float* Wo  = (const float*)d_in[14]; const float* bo  = (const float*)d_in[15];
    float* out = (float*)d_out;

    char* ws = (char*)d_ws;
    size_t off = 0;
    auto alloc = [&](size_t bytes) -> void* {
        void* p = ws + off;
        off = (off + bytes + 255) & ~(size_t)255;
        return p;
    };
    unsigned short* wbf[6];
    for (int i = 0; i < 6; ++i) wbf[i] = (unsigned short*)alloc((size_t)EMBED * EMBED * 2);
    unsigned short* wo2 = (unsigned short*)alloc((size_t)HIDDEN * KTOT * 2);
    unsigned short* qkv[6];
    for (int i = 0; i < 6; ++i) qkv[i] = (unsigned short*)alloc((size_t)BB * EMBED * HWN * 2);
    unsigned short* fused2 = (unsigned short*)alloc((size_t)BB * HWN * KTOT * 2);

    // 1) weights -> bf16 (Wo duplicated into Wo2)
    WConv wc;
    const float* wsrc[7] = {Wq, Wk, Wv, Wqb, Wkb, Wvb, Wo};
    unsigned short* wdst[7] = {wbf[0], wbf[1], wbf[2], wbf[3], wbf[4], wbf[5], wo2};
    int acc4 = 0;
    for (int i = 0; i < 7; ++i) {
        const int n = (i < 6) ? EMBED * EMBED : HIDDEN * 768;
        wc.src[i] = wsrc[i];
        wc.dst[i] = wdst[i];
        wc.start[i] = acc4;
        acc4 += n / 4;
    }
    wc.start[7] = acc4;
    k_bf16_all<<<(acc4 + 255) / 256, 256, 0, stream>>>(wc);

    // 2) x, x_bpf -> token-major bf16 into fused2 cols 768..1535
    k_transpose<<<dim3(EMBED / 32, HWN / 32, 16), 256, 0, stream>>>(x, xbp, fused2);

    // 3) six QKV projections (128x128 tiles)
    QkvTable tab;
    tab.W[0] = wbf[0]; tab.W[1] = wbf[1]; tab.W[2] = wbf[2];
    tab.W[3] = wbf[3]; tab.W[4] = wbf[4]; tab.W[5] = wbf[5];
    tab.bias[0] = bq; tab.bias[1] = bk; tab.bias[2] = bv;
    tab.bias[3] = bqb; tab.bias[4] = bkb; tab.bias[5] = bvb;
    tab.fused2 = fused2;
    for (int i = 0; i < 6; ++i) tab.out[i] = qkv[i];
    k_gemm_qkv<<<dim3(EMBED / 128, HWN / 128, BB * 6), 256, 0, stream>>>(tab);

    // 4) MFMA attention -> fused2 cols 0..767 (512 instances x 4 q-tiles of 256, XCD-local)
    k_attn_mfma<<<dim3(2048), 256, 0, stream>>>(qkv[0], qkv[1], qkv[2], qkv[3], qkv[4], qkv[5],
                                                fused2);

    // 5) out = Wo2 . fused2 + bo   (K=1536 folds the residual)
    k_gemm_out<<<dim3(HIDDEN / 128, HWN / 128, BB), 256, 0, stream>>>(wo2, fused2, bo, out);
}

// Round 23
// 165.069 us; speedup vs baseline: 1.0765x; 1.0045x over previous
//
#include <hip/hip_runtime.h>
#include <hip/hip_bf16.h>

#define BB 8
#define EMBED 384
#define NH 32
#define HD 12
#define HWN 1024
#define HIDDEN 512
#define KTOT 1536
#define SCALE 0.28867513459481287f

typedef __attribute__((ext_vector_type(8))) unsigned short ushort8;
typedef __attribute__((ext_vector_type(8))) short short8;
typedef __attribute__((ext_vector_type(4))) float f32x4;
typedef __attribute__((ext_vector_type(16))) float f32x16;
typedef __attribute__((ext_vector_type(4))) unsigned short ushort4v;
typedef __attribute__((ext_vector_type(2))) unsigned int uint2v;

static __device__ __forceinline__ float bf2f(unsigned short u) {
    return __uint_as_float(((unsigned int)u) << 16);
}
static __device__ __forceinline__ unsigned short f2bf(float f) {
    unsigned int u = __float_as_uint(f);
    u = u + 0x7FFFu + ((u >> 16) & 1u);   // RNE
    return (unsigned short)(u >> 16);
}
static __device__ __forceinline__ unsigned int cvt_pk_bf16(float lo, float hi) {
    unsigned int r;
    asm("v_cvt_pk_bf16_f32 %0, %1, %2" : "=v"(r) : "v"(lo), "v"(hi));
    return r;
}

#if __has_builtin(__builtin_amdgcn_global_load_lds)
#define HAVE_GLOAD_LDS 1
static __device__ __forceinline__ void gl_lds16(const unsigned short* g, unsigned short* l) {
    __builtin_amdgcn_global_load_lds(
        (const __attribute__((address_space(1))) unsigned int*)g,
        (__attribute__((address_space(3))) unsigned int*)l, 16, 0, 0);
}
#else
#define HAVE_GLOAD_LDS 0
#endif

// ---------------- f32 -> bf16 weights; Wo duplicated into Wo2[512][1536] ----------------
struct WConv {
    const float* src[7];
    unsigned short* dst[7];
    int start[8];   // prefix over vec4 counts
};

__global__ __launch_bounds__(256) void k_bf16_all(WConv wc) {
    int i = blockIdx.x * 256 + threadIdx.x;
    if (i >= wc.start[7]) return;
    int p = 0;
#pragma unroll
    for (int j = 1; j < 7; ++j) p += (i >= wc.start[j]);
    const int e = i - wc.start[p];
    const f32x4 v = reinterpret_cast<const f32x4*>(wc.src[p])[e];
    ushort4v o;
#pragma unroll
    for (int j = 0; j < 4; ++j) o[j] = f2bf(v[j]);
    if (p == 6) {
        const int row = e / 192, cc = e % 192;
        ushort4v* d = reinterpret_cast<ushort4v*>(wc.dst[6]);
        d[row * 384 + cc] = o;
        d[row * 384 + 192 + cc] = o;
    } else {
        reinterpret_cast<ushort4v*>(wc.dst[p])[e] = o;
    }
}

// ---------------- transpose x (B,C,HW) f32 -> fused2[b][n][768 + s*384 + c] bf16 ----------------
__global__ __launch_bounds__(256) void k_transpose(const float* __restrict__ x0, const float* __restrict__ x1,
                                                   unsigned short* __restrict__ fused2) {
    __shared__ float tile[32][33];
    const int z = blockIdx.z;
    const int s = z >> 3, b = z & 7;
    const float* src = (s ? x1 : x0) + (size_t)b * EMBED * HWN;
    unsigned short* dst = fused2 + (size_t)b * HWN * KTOT + 768 + s * 384;
    const int c0 = blockIdx.x * 32;
    const int n0 = blockIdx.y * 32;
    const int tc = threadIdx.x & 31;
    const int tr = threadIdx.x >> 5;
#pragma unroll
    for (int p = 0; p < 4; ++p) {
        int r = tr + p * 8;
        tile[r][tc] = src[(size_t)(c0 + r) * HWN + n0 + tc];
    }
    __syncthreads();
#pragma unroll
    for (int p = 0; p < 4; ++p) {
        int r = tr + p * 8;
        dst[(size_t)(n0 + r) * KTOT + c0 + tc] = f2bf(tile[tc][r]);
    }
}

// ---------------- bf16 MFMA GEMM 128x128xBK64 (m97 structure) ----------------
template <bool F32OUT>
static __device__ __forceinline__ void gemm128(const unsigned short* __restrict__ A, int lda,
                                               const unsigned short* __restrict__ Bt, int ldb,
                                               const float* __restrict__ bias,
                                               unsigned short* __restrict__ outBf,
                                               float* __restrict__ outF,
                                               int K, int bx, int by) {
    __shared__ unsigned short As[128][64];
    __shared__ unsigned short Bs[128][64];
    const int t = threadIdx.x;
    const int lane = t & 63;
    const int w = t >> 6;
    const int wr = w >> 1, wc = w & 1;
    const int o0 = bx * 128, n0 = by * 128;
    const int srow = lane >> 3;
    const int scol = (lane & 7) * 8;

    f32x4 acc[4][4] = {};

    for (int k0 = 0; k0 < K; k0 += 64) {
#pragma unroll
        for (int i = 0; i < 4; ++i) {
            const int c = w * 4 + i;
            const int r = c * 8 + srow;
#if HAVE_GLOAD_LDS
            gl_lds16(A + (size_t)(o0 + r) * lda + k0 + scol, &As[c * 8][0]);
            gl_lds16(Bt + (size_t)(n0 + r) * ldb + k0 + scol, &Bs[c * 8][0]);
#else
            *reinterpret_cast<ushort8*>(&As[r][scol]) =
                *reinterpret_cast<const ushort8*>(A + (size_t)(o0 + r) * lda + k0 + scol);
            *reinterpret_cast<ushort8*>(&Bs[r][scol]) =
                *reinterpret_cast<const ushort8*>(Bt + (size_t)(n0 + r) * ldb + k0 + scol);
#endif
        }
        __syncthreads();
#pragma unroll
        for (int kk = 0; kk < 2; ++kk) {
            const int ko = kk * 32 + ((lane >> 4) << 3);
            short8 af[4], bf[4];
#pragma unroll
            for (int i = 0; i < 4; ++i) {
                af[i] = *reinterpret_cast<const short8*>(&As[wr * 64 + i * 16 + (lane & 15)][ko]);
                bf[i] = *reinterpret_cast<const short8*>(&Bs[wc * 64 + i * 16 + (lane & 15)][ko]);
            }
#pragma unroll
            for (int i = 0; i < 4; ++i)
#pragma unroll
                for (int j = 0; j < 4; ++j)
                    acc[i][j] = __builtin_amdgcn_mfma_f32_16x16x32_bf16(af[i], bf[j], acc[i][j], 0, 0, 0);
        }
        __syncthreads();
    }
#pragma unroll
    for (int i = 0; i < 4; ++i) {
#pragma unroll
        for (int j = 0; j < 4; ++j) {
            const int ob = o0 + wr * 64 + i * 16 + ((lane >> 4) << 2);
            const int n  = n0 + wc * 64 + j * 16 + (lane & 15);
#pragma unroll
            for (int r = 0; r < 4; ++r) {
                const int o = ob + r;
                float v = acc[i][j][r] + bias[o];
                if constexpr (F32OUT) outF[(size_t)o * HWN + n] = v;
                else                  outBf[(size_t)o * HWN + n] = f2bf(v);
            }
        }
    }
}

struct QkvTable {
    const unsigned short* W[6];
    const float* bias[6];
    const unsigned short* fused2;
    unsigned short* out[6];
};

__global__ __launch_bounds__(256) void k_gemm_qkv(QkvTable tab) {
    const int z = blockIdx.z;
    const int b = z / 6, p = z % 6;
    const unsigned short* Bt = tab.fused2 + (size_t)b * HWN * KTOT + 768 + (p / 3) * 384;
    gemm128<false>(tab.W[p], EMBED, Bt, KTOT, tab.bias[p],
                   tab.out[p] + (size_t)b * EMBED * HWN, nullptr,
                   EMBED, blockIdx.x, blockIdx.y);
}

__global__ __launch_bounds__(256) void k_gemm_out(const unsigned short* __restrict__ Wo2,
                                                  const unsigned short* __restrict__ fused2,
                                                  const float* __restrict__ bo,
                                                  float* __restrict__ out) {
    const int b = blockIdx.z;
    gemm128<true>(Wo2, KTOT, fused2 + (size_t)b * HWN * KTOT, KTOT, bo,
                  nullptr, out + (size_t)b * HIDDEN * HWN,
                  KTOT, blockIdx.x, blockIdx.y);
}

// ---------------- MFMA flash attention v10: max-TLP config ----------------
// 1 q-frag/wave (128 q/block, grid 4096) + XCD-local inst mapping + 4-phase 15.7KB LDS + setprio.
// VGPR ~60 -> 8 waves/SIMD allowed: double the independent blocks vs v8 at identical FETCH/conflicts.
#define OT_STRIDE 416
__global__ __launch_bounds__(256) void k_attn_mfma(const unsigned short* __restrict__ qc,
                                                   const unsigned short* __restrict__ kc,
                                                   const unsigned short* __restrict__ vc,
                                                   const unsigned short* __restrict__ qcb,
                                                   const unsigned short* __restrict__ kcb,
                                                   const unsigned short* __restrict__ vcb,
                                                   unsigned short* __restrict__ fused2) {
    __shared__ unsigned short Ks[256][18];   // [m][d 0..15 + 2 pad], 36B rows (9 dw, coprime 32)
    __shared__ unsigned short Vs[13][264];   // [d][m], row 12 = ones

    const int bid = blockIdx.x;
    const int inst = bid & 511, qt = bid >> 9;      // blocks sharing inst are 512 apart -> same XCD
    const int branch = inst >> 8, b = (inst >> 5) & 7, h = inst & 31;
    const unsigned short* Qg = branch ? qc : qcb;
    const unsigned short* Kg = branch ? kcb : kc;
    const unsigned short* Vg = branch ? vcb : vc;
    const int coff = branch ? 384 : 0;
    const size_t base = ((size_t)b * EMBED + h * HD) * HWN;
    const int t = threadIdx.x;
    const int lane = t & 63, w = t >> 6;
    const int q31 = lane & 31, hi = lane >> 5;
    const int n0 = qt * 128;
    const float C2 = SCALE * 1.4426950408889634f;

    // Q B-frag (32x32x16): lane (q31,hi) holds Q[d=hi*8+j][q = n0 + w*32 + q31], pre-scaled by C2
    short8 qf = {};
    {
        const int qg = n0 + w * 32 + q31;
#pragma unroll
        for (int j = 0; j < 8; ++j) {
            const int d = hi * 8 + j;
            if (d < HD)
                qf[j] = (short)f2bf(bf2f(Qg[base + (size_t)d * HWN + qg]) * C2);
        }
    }

    f32x16 acc, z16;
#pragma unroll
    for (int r = 0; r < 16; ++r) { acc[r] = 0.f; z16[r] = 0.f; }
    const int vrow = (q31 < HD) ? q31 : 12;   // lanes d>=12 read ones row (outputs discarded)

    for (int phase = 0; phase < 4; ++phase) {
        const int m0 = phase << 8;
        __syncthreads();   // prior-phase reads done
        // --- stage K (256 m): wave w owns d-rows 4w..4w+3 (w=3 -> zeros). 128B-coalesced gathers.
        {
            const size_t kb = base + (size_t)(4 * w) * HWN + m0;
#pragma unroll
            for (int it = 0; it < 4; ++it) {
                const int m = it * 64 + lane;
                unsigned int da = 0, db = 0;
                if (w < 3) {
                    da = (unsigned int)Kg[kb + m] | ((unsigned int)Kg[kb + HWN + m] << 16);
                    db = (unsigned int)Kg[kb + 2 * HWN + m] | ((unsigned int)Kg[kb + 3 * HWN + m] << 16);
                }
                unsigned int* p = reinterpret_cast<unsigned int*>(&Ks[m][w * 4]);
                p[0] = da;
                p[1] = db;
            }
        }
        // --- stage V (256 m): wave w<3 owns d-rows 4w..4w+3; w==3 lanes<32 write ones row (d=12)
        if (w < 3) {
#pragma unroll
            for (int r2 = 0; r2 < 2; ++r2) {
                const int d = 4 * w + 2 * r2 + (lane >> 5);
                const int col = (lane & 31) * 8;
                *reinterpret_cast<ushort8*>(&Vs[d][col]) =
                    *reinterpret_cast<const ushort8*>(&Vg[base + (size_t)d * HWN + m0 + col]);
            }
        } else if (lane < 32) {
            ushort8 ones;
#pragma unroll
            for (int j = 0; j < 8; ++j) ones[j] = 0x3F80;
            *reinterpret_cast<ushort8*>(&Vs[12][lane * 8]) = ones;
        }
        __syncthreads();

        __builtin_amdgcn_s_setprio(1);
        for (int mc = 0; mc < 8; ++mc) {
            const int mb = mc << 5;
            // K A-frag: lane (m-local = q31, hi) = K[mb+q31][d = hi*8+j]; dword loads (36B rows)
            union { short8 v; unsigned int u[4]; } kf;
            {
                const unsigned int* kp = reinterpret_cast<const unsigned int*>(&Ks[mb + q31][hi * 8]);
                kf.u[0] = kp[0]; kf.u[1] = kp[1]; kf.u[2] = kp[2]; kf.u[3] = kp[3];
            }
            // V B-frags, sigma-permuted k-rows: PV1 m {0..3,8..11}+4hi, PV2 +16
            union { short8 v; uint2v u2[2]; } vf1, vf2;
            vf1.u2[0] = *reinterpret_cast<const uint2v*>(&Vs[vrow][mb + hi * 4]);
            vf1.u2[1] = *reinterpret_cast<const uint2v*>(&Vs[vrow][mb + 8 + hi * 4]);
            vf2.u2[0] = *reinterpret_cast<const uint2v*>(&Vs[vrow][mb + 16 + hi * 4]);
            vf2.u2[1] = *reinterpret_cast<const uint2v*>(&Vs[vrow][mb + 24 + hi * 4]);
            // QKT: C reg r = P[m=(r&3)+8*(r>>2)+4hi][q=q31]
            const f32x16 s = __builtin_amdgcn_mfma_f32_32x32x16_bf16(kf.v, qf, z16, 0, 0, 0);
            union { short8 v; unsigned int u[4]; } p1, p2;
#pragma unroll
            for (int r = 0; r < 4; ++r) {
                p1.u[r] = cvt_pk_bf16(__builtin_amdgcn_exp2f(s[2 * r]),
                                      __builtin_amdgcn_exp2f(s[2 * r + 1]));
                p2.u[r] = cvt_pk_bf16(__builtin_amdgcn_exp2f(s[8 + 2 * r]),
                                      __builtin_amdgcn_exp2f(s[8 + 2 * r + 1]));
            }
            acc = __builtin_amdgcn_mfma_f32_32x32x16_bf16(p1.v, vf1.v, acc, 0, 0, 0);
            acc = __builtin_amdgcn_mfma_f32_32x32x16_bf16(p2.v, vf2.v, acc, 0, 0, 0);
        }
        __builtin_amdgcn_s_setprio(0);
    }

    // inverse row-sums: output col 12 (ones row) at lane (lane&32)|12, same reg
    float invq[16];
#pragma unroll
    for (int r = 0; r < 16; ++r)
        invq[r] = 1.0f / __shfl(acc[r], (lane & 32) | 12);

    __syncthreads();   // all Ks/Vs reads done before Ot overwrites Ks
    // Ot per wave: [12 d][32 q] shorts at stride OT_STRIDE, block index = w
    {
        unsigned short* OtW = &Ks[0][0] + w * OT_STRIDE;
        if (q31 < HD) {
#pragma unroll
            for (int r2 = 0; r2 < 8; ++r2) {
                const int r = 2 * r2;
                const int q = (r & 3) + 8 * (r >> 2) + 4 * hi;
                const unsigned int dw = (unsigned int)f2bf(acc[r] * invq[r]) |
                                        ((unsigned int)f2bf(acc[r + 1] * invq[r + 1]) << 16);
                *reinterpret_cast<unsigned int*>(&OtW[q31 * 32 + q]) = dw;
            }
        }
    }
    __syncthreads();
    // store: 128 q, 256 threads: q = t>>1, half = t&1 covers d 0..5 / 6..11
    {
        const int q = t >> 1, half = t & 1;
        const unsigned short* Osrc = &Ks[0][0] + (q >> 5) * OT_STRIDE + (half * 6) * 32 + (q & 31);
        unsigned int dwv[3];
#pragma unroll
        for (int dp = 0; dp < 3; ++dp)
            dwv[dp] = (unsigned int)Osrc[(2 * dp) * 32] | ((unsigned int)Osrc[(2 * dp + 1) * 32] << 16);
        unsigned int* dst = reinterpret_cast<unsigned int*>(
            fused2 + ((size_t)b * HWN + n0 + q) * KTOT + coff + h * HD + half * 6);
#pragma unroll
        for (int dp = 0; dp < 3; ++dp) dst[dp] = dwv[dp];
    }
}

extern "C" void kernel_launch(void* const* d_in, const int* in_sizes, int n_in,
                              void* d_out, int out_size, void* d_ws, size_t ws_size,
                              hipStream_t stream) {
    (void)in_sizes; (void)n_in; (void)out_size; (void)ws_size;
    const float* x   = (const float*)d_in[0];
    const float* xbp = (const float*)d_in[1];
    const float* Wq  = (const float*)d_in[2];  const float* bq  = (const float*)d_in[3];
    const float* Wk  = (const float*)d_in[4];  const float* bk  = (const float*)d_in[5];
    const float* Wv  = (const float*)d_in[6];  const float* bv  = (const float*)d_in[7];
    const float* Wqb = (const float*)d_in[8];  const float* bqb = (const float*)d_in[9];
    const float* Wkb = (const float*)d_in[10]; const float* bkb = (const float*)d_in[11];
    const float* Wvb = (const float*)d_in[12]; const float* bvb = (const float*)d_in[13];
    const float* Wo  = (const float*)d_in[14]; const float* bo  = (const float*)d_in[15];
    float* out = (float*)d_out;

    char* ws = (char*)d_ws;
    size_t off = 0;
    auto alloc = [&](size_t bytes) -> void* {
        void* p = ws + off;
        off = (off + bytes + 255) & ~(size_t)255;
        return p;
    };
    unsigned short* wbf[6];
    for (int i = 0; i < 6; ++i) wbf[i] = (unsigned short*)alloc((size_t)EMBED * EMBED * 2);
    unsigned short* wo2 = (unsigned short*)alloc((size_t)HIDDEN * KTOT * 2);
    unsigned short* qkv[6];
    for (int i = 0; i < 6; ++i) qkv[i] = (unsigned short*)alloc((size_t)BB * EMBED * HWN * 2);
    unsigned short* fused2 = (unsigned short*)alloc((size_t)BB * HWN * KTOT * 2);

    // 1) weights -> bf16 (Wo duplicated into Wo2)
    WConv wc;
    const float* wsrc[7] = {Wq, Wk, Wv, Wqb, Wkb, Wvb, Wo};
    unsigned short* wdst[7] = {wbf[0], wbf[1], wbf[2], wbf[3], wbf[4], wbf[5], wo2};
    int acc4 = 0;
    for (int i = 0; i < 7; ++i) {
        const int n = (i < 6) ? EMBED * EMBED : HIDDEN * 768;
        wc.src[i] = wsrc[i];
        wc.dst[i] = wdst[i];
        wc.start[i] = acc4;
        acc4 += n / 4;
    }
    wc.start[7] = acc4;
    k_bf16_all<<<(acc4 + 255) / 256, 256, 0, stream>>>(wc);

    // 2) x, x_bpf -> token-major bf16 into fused2 cols 768..1535
    k_transpose<<<dim3(EMBED / 32, HWN / 32, 16), 256, 0, stream>>>(x, xbp, fused2);

    // 3) six QKV projections (128x128 tiles)
    QkvTable tab;
    tab.W[0] = wbf[0]; tab.W[1] = wbf[1]; tab.W[2] = wbf[2];
    tab.W[3] = wbf[3]; tab.W[4] = wbf[4]; tab.W[5] = wbf[5];
    tab.bias[0] = bq; tab.bias[1] = bk; tab.bias[2] = bv;
    tab.bias[3] = bqb; tab.bias[4] = bkb; tab.bias[5] = bvb;
    tab.fused2 = fused2;
    for (int i = 0; i < 6; ++i) tab.out[i] = qkv[i];
    k_gemm_qkv<<<dim3(EMBED / 128, HWN / 128, BB * 6), 256, 0, stream>>>(tab);

    // 4) MFMA attention -> fused2 cols 0..767 (512 instances x 8 q-tiles of 128, XCD-local)
    k_attn_mfma<<<dim3(4096), 256, 0, stream>>>(qkv[0], qkv[1], qkv[2], qkv[3], qkv[4], qkv[5],
                                                fused2);

    // 5) out = Wo2 . fused2 + bo   (K=1536 folds the residual)
    k_gemm_out<<<dim3(HIDDEN / 128, HWN / 128, BB), 256, 0, stream>>>(wo2, fused2, bo, out);
}

// Round 24
// 159.061 us; speedup vs baseline: 1.1172x; 1.0378x over previous
//
#include <hip/hip_runtime.h>
#include <hip/hip_bf16.h>

#define BB 8
#define EMBED 384
#define NH 32
#define HD 12
#define HWN 1024
#define HIDDEN 512
#define KTOT 1536
#define SCALE 0.28867513459481287f

typedef __attribute__((ext_vector_type(8))) unsigned short ushort8;
typedef __attribute__((ext_vector_type(8))) short short8;
typedef __attribute__((ext_vector_type(4))) float f32x4;
typedef __attribute__((ext_vector_type(16))) float f32x16;
typedef __attribute__((ext_vector_type(4))) unsigned short ushort4v;
typedef __attribute__((ext_vector_type(2))) unsigned int uint2v;

static __device__ __forceinline__ float bf2f(unsigned short u) {
    return __uint_as_float(((unsigned int)u) << 16);
}
static __device__ __forceinline__ unsigned short f2bf(float f) {
    unsigned int u = __float_as_uint(f);
    u = u + 0x7FFFu + ((u >> 16) & 1u);   // RNE
    return (unsigned short)(u >> 16);
}
static __device__ __forceinline__ unsigned int cvt_pk_bf16(float lo, float hi) {
    unsigned int r;
    asm("v_cvt_pk_bf16_f32 %0, %1, %2" : "=v"(r) : "v"(lo), "v"(hi));
    return r;
}

#if __has_builtin(__builtin_amdgcn_global_load_lds)
#define HAVE_GLOAD_LDS 1
static __device__ __forceinline__ void gl_lds16(const unsigned short* g, unsigned short* l) {
    __builtin_amdgcn_global_load_lds(
        (const __attribute__((address_space(1))) unsigned int*)g,
        (__attribute__((address_space(3))) unsigned int*)l, 16, 0, 0);
}
#else
#define HAVE_GLOAD_LDS 0
#endif

// ---------------- f32 -> bf16 weights; Wo duplicated into Wo2[512][1536] ----------------
struct WConv {
    const float* src[7];
    unsigned short* dst[7];
    int start[8];   // prefix over vec4 counts
};

__global__ __launch_bounds__(256) void k_bf16_all(WConv wc) {
    int i = blockIdx.x * 256 + threadIdx.x;
    if (i >= wc.start[7]) return;
    int p = 0;
#pragma unroll
    for (int j = 1; j < 7; ++j) p += (i >= wc.start[j]);
    const int e = i - wc.start[p];
    const f32x4 v = reinterpret_cast<const f32x4*>(wc.src[p])[e];
    ushort4v o;
#pragma unroll
    for (int j = 0; j < 4; ++j) o[j] = f2bf(v[j]);
    if (p == 6) {
        const int row = e / 192, cc = e % 192;
        ushort4v* d = reinterpret_cast<ushort4v*>(wc.dst[6]);
        d[row * 384 + cc] = o;
        d[row * 384 + 192 + cc] = o;
    } else {
        reinterpret_cast<ushort4v*>(wc.dst[p])[e] = o;
    }
}

// ---------------- transpose x (B,C,HW) f32 -> fused2[b][n][768 + s*384 + c] bf16 ----------------
__global__ __launch_bounds__(256) void k_transpose(const float* __restrict__ x0, const float* __restrict__ x1,
                                                   unsigned short* __restrict__ fused2) {
    __shared__ float tile[32][33];
    const int z = blockIdx.z;
    const int s = z >> 3, b = z & 7;
    const float* src = (s ? x1 : x0) + (size_t)b * EMBED * HWN;
    unsigned short* dst = fused2 + (size_t)b * HWN * KTOT + 768 + s * 384;
    const int c0 = blockIdx.x * 32;
    const int n0 = blockIdx.y * 32;
    const int tc = threadIdx.x & 31;
    const int tr = threadIdx.x >> 5;
#pragma unroll
    for (int p = 0; p < 4; ++p) {
        int r = tr + p * 8;
        tile[r][tc] = src[(size_t)(c0 + r) * HWN + n0 + tc];
    }
    __syncthreads();
#pragma unroll
    for (int p = 0; p < 4; ++p) {
        int r = tr + p * 8;
        dst[(size_t)(n0 + r) * KTOT + c0 + tc] = f2bf(tile[tc][r]);
    }
}

// ---------------- bf16 MFMA GEMM 128x128xBK64 + st_16x32-style XOR swizzle (G4/m201/rule #21) ----------------
// LDS tiles have 128B rows -> unswizzled frag reads are 16-way bank-conflicted. Fix: linear LDS
// dest (gl_lds requirement) + pre-swizzled GLOBAL source column (lane l loads colbyte
// ((l&7)^(l>>3))*16) + XOR (row&7)<<4 on the read side. Same cache lines, 16-way -> 2-way.
template <bool F32OUT>
static __device__ __forceinline__ void gemm128(const unsigned short* __restrict__ A, int lda,
                                               const unsigned short* __restrict__ Bt, int ldb,
                                               const float* __restrict__ bias,
                                               unsigned short* __restrict__ outBf,
                                               float* __restrict__ outF,
                                               int K, int bx, int by) {
    __shared__ unsigned short As[128][64];
    __shared__ unsigned short Bs[128][64];
    const int t = threadIdx.x;
    const int lane = t & 63;
    const int w = t >> 6;
    const int wr = w >> 1, wc = w & 1;
    const int o0 = bx * 128, n0 = by * 128;
    const int srow = lane >> 3;                              // 0..7 within chunk
    const int scol = (((lane & 7) ^ (lane >> 3)) << 3);      // swizzled source col (elements)

    f32x4 acc[4][4] = {};

    for (int k0 = 0; k0 < K; k0 += 64) {
#pragma unroll
        for (int i = 0; i < 4; ++i) {
            const int c = w * 4 + i;
            const int r = c * 8 + srow;
#if HAVE_GLOAD_LDS
            gl_lds16(A + (size_t)(o0 + r) * lda + k0 + scol, &As[c * 8][0]);
            gl_lds16(Bt + (size_t)(n0 + r) * ldb + k0 + scol, &Bs[c * 8][0]);
#else
            // linear LDS slot (r, (lane&7)*16B) <- global swizzled col (same involution)
            *reinterpret_cast<ushort8*>(&As[r][(lane & 7) * 8]) =
                *reinterpret_cast<const ushort8*>(A + (size_t)(o0 + r) * lda + k0 + scol);
            *reinterpret_cast<ushort8*>(&Bs[r][(lane & 7) * 8]) =
                *reinterpret_cast<const ushort8*>(Bt + (size_t)(n0 + r) * ldb + k0 + scol);
#endif
        }
        __syncthreads();
#pragma unroll
        for (int kk = 0; kk < 2; ++kk) {
            const int ko = kk * 32 + ((lane >> 4) << 3);
            const int xorb = (lane & 7) << 4;   // (R&7)<<4, R&7 == lane&7 for all frags
            short8 af[4], bf[4];
#pragma unroll
            for (int i = 0; i < 4; ++i) {
                const int ra = wr * 64 + i * 16 + (lane & 15);
                const int rb = wc * 64 + i * 16 + (lane & 15);
                af[i] = *reinterpret_cast<const short8*>(
                    reinterpret_cast<const char*>(&As[0][0]) + ra * 128 + ((ko * 2) ^ xorb));
                bf[i] = *reinterpret_cast<const short8*>(
                    reinterpret_cast<const char*>(&Bs[0][0]) + rb * 128 + ((ko * 2) ^ xorb));
            }
#pragma unroll
            for (int i = 0; i < 4; ++i)
#pragma unroll
                for (int j = 0; j < 4; ++j)
                    acc[i][j] = __builtin_amdgcn_mfma_f32_16x16x32_bf16(af[i], bf[j], acc[i][j], 0, 0, 0);
        }
        __syncthreads();
    }
#pragma unroll
    for (int i = 0; i < 4; ++i) {
#pragma unroll
        for (int j = 0; j < 4; ++j) {
            const int ob = o0 + wr * 64 + i * 16 + ((lane >> 4) << 2);
            const int n  = n0 + wc * 64 + j * 16 + (lane & 15);
#pragma unroll
            for (int r = 0; r < 4; ++r) {
                const int o = ob + r;
                float v = acc[i][j][r] + bias[o];
                if constexpr (F32OUT) outF[(size_t)o * HWN + n] = v;
                else                  outBf[(size_t)o * HWN + n] = f2bf(v);
            }
        }
    }
}

struct QkvTable {
    const unsigned short* W[6];
    const float* bias[6];
    const unsigned short* fused2;
    unsigned short* out[6];
};

__global__ __launch_bounds__(256) void k_gemm_qkv(QkvTable tab) {
    const int z = blockIdx.z;
    const int b = z / 6, p = z % 6;
    const unsigned short* Bt = tab.fused2 + (size_t)b * HWN * KTOT + 768 + (p / 3) * 384;
    gemm128<false>(tab.W[p], EMBED, Bt, KTOT, tab.bias[p],
                   tab.out[p] + (size_t)b * EMBED * HWN, nullptr,
                   EMBED, blockIdx.x, blockIdx.y);
}

__global__ __launch_bounds__(256) void k_gemm_out(const unsigned short* __restrict__ Wo2,
                                                  const unsigned short* __restrict__ fused2,
                                                  const float* __restrict__ bo,
                                                  float* __restrict__ out) {
    const int b = blockIdx.z;
    gemm128<true>(Wo2, KTOT, fused2 + (size_t)b * HWN * KTOT, KTOT, bo,
                  nullptr, out + (size_t)b * HIDDEN * HWN,
                  KTOT, blockIdx.x, blockIdx.y);
}

// ---------------- MFMA flash attention v10 (round-23 verified): max-TLP config ----------------
#define OT_STRIDE 416
__global__ __launch_bounds__(256) void k_attn_mfma(const unsigned short* __restrict__ qc,
                                                   const unsigned short* __restrict__ kc,
                                                   const unsigned short* __restrict__ vc,
                                                   const unsigned short* __restrict__ qcb,
                                                   const unsigned short* __restrict__ kcb,
                                                   const unsigned short* __restrict__ vcb,
                                                   unsigned short* __restrict__ fused2) {
    __shared__ unsigned short Ks[256][18];   // [m][d 0..15 + 2 pad], 36B rows (9 dw, coprime 32)
    __shared__ unsigned short Vs[13][264];   // [d][m], row 12 = ones

    const int bid = blockIdx.x;
    const int inst = bid & 511, qt = bid >> 9;      // blocks sharing inst are 512 apart -> same XCD
    const int branch = inst >> 8, b = (inst >> 5) & 7, h = inst & 31;
    const unsigned short* Qg = branch ? qc : qcb;
    const unsigned short* Kg = branch ? kcb : kc;
    const unsigned short* Vg = branch ? vcb : vc;
    const int coff = branch ? 384 : 0;
    const size_t base = ((size_t)b * EMBED + h * HD) * HWN;
    const int t = threadIdx.x;
    const int lane = t & 63, w = t >> 6;
    const int q31 = lane & 31, hi = lane >> 5;
    const int n0 = qt * 128;
    const float C2 = SCALE * 1.4426950408889634f;

    // Q B-frag (32x32x16): lane (q31,hi) holds Q[d=hi*8+j][q = n0 + w*32 + q31], pre-scaled by C2
    short8 qf = {};
    {
        const int qg = n0 + w * 32 + q31;
#pragma unroll
        for (int j = 0; j < 8; ++j) {
            const int d = hi * 8 + j;
            if (d < HD)
                qf[j] = (short)f2bf(bf2f(Qg[base + (size_t)d * HWN + qg]) * C2);
        }
    }

    f32x16 acc, z16;
#pragma unroll
    for (int r = 0; r < 16; ++r) { acc[r] = 0.f; z16[r] = 0.f; }
    const int vrow = (q31 < HD) ? q31 : 12;   // lanes d>=12 read ones row (outputs discarded)

    for (int phase = 0; phase < 4; ++phase) {
        const int m0 = phase << 8;
        __syncthreads();   // prior-phase reads done
        // --- stage K (256 m): wave w owns d-rows 4w..4w+3 (w=3 -> zeros). 128B-coalesced gathers.
        {
            const size_t kb = base + (size_t)(4 * w) * HWN + m0;
#pragma unroll
            for (int it = 0; it < 4; ++it) {
                const int m = it * 64 + lane;
                unsigned int da = 0, db = 0;
                if (w < 3) {
                    da = (unsigned int)Kg[kb + m] | ((unsigned int)Kg[kb + HWN + m] << 16);
                    db = (unsigned int)Kg[kb + 2 * HWN + m] | ((unsigned int)Kg[kb + 3 * HWN + m] << 16);
                }
                unsigned int* p = reinterpret_cast<unsigned int*>(&Ks[m][w * 4]);
                p[0] = da;
                p[1] = db;
            }
        }
        // --- stage V (256 m): wave w<3 owns d-rows 4w..4w+3; w==3 lanes<32 write ones row (d=12)
        if (w < 3) {
#pragma unroll
            for (int r2 = 0; r2 < 2; ++r2) {
                const int d = 4 * w + 2 * r2 + (lane >> 5);
                const int col = (lane & 31) * 8;
                *reinterpret_cast<ushort8*>(&Vs[d][col]) =
                    *reinterpret_cast<const ushort8*>(&Vg[base + (size_t)d * HWN + m0 + col]);
            }
        } else if (lane < 32) {
            ushort8 ones;
#pragma unroll
            for (int j = 0; j < 8; ++j) ones[j] = 0x3F80;
            *reinterpret_cast<ushort8*>(&Vs[12][lane * 8]) = ones;
        }
        __syncthreads();

        __builtin_amdgcn_s_setprio(1);
        for (int mc = 0; mc < 8; ++mc) {
            const int mb = mc << 5;
            // K A-frag: lane (m-local = q31, hi) = K[mb+q31][d = hi*8+j]; dword loads (36B rows)
            union { short8 v; unsigned int u[4]; } kf;
            {
                const unsigned int* kp = reinterpret_cast<const unsigned int*>(&Ks[mb + q31][hi * 8]);
                kf.u[0] = kp[0]; kf.u[1] = kp[1]; kf.u[2] = kp[2]; kf.u[3] = kp[3];
            }
            // V B-frags, sigma-permuted k-rows: PV1 m {0..3,8..11}+4hi, PV2 +16
            union { short8 v; uint2v u2[2]; } vf1, vf2;
            vf1.u2[0] = *reinterpret_cast<const uint2v*>(&Vs[vrow][mb + hi * 4]);
            vf1.u2[1] = *reinterpret_cast<const uint2v*>(&Vs[vrow][mb + 8 + hi * 4]);
            vf2.u2[0] = *reinterpret_cast<const uint2v*>(&Vs[vrow][mb + 16 + hi * 4]);
            vf2.u2[1] = *reinterpret_cast<const uint2v*>(&Vs[vrow][mb + 24 + hi * 4]);
            // QKT: C reg r = P[m=(r&3)+8*(r>>2)+4hi][q=q31]
            const f32x16 s = __builtin_amdgcn_mfma_f32_32x32x16_bf16(kf.v, qf, z16, 0, 0, 0);
            union { short8 v; unsigned int u[4]; } p1, p2;
#pragma unroll
            for (int r = 0; r < 4; ++r) {
                p1.u[r] = cvt_pk_bf16(__builtin_amdgcn_exp2f(s[2 * r]),
                                      __builtin_amdgcn_exp2f(s[2 * r + 1]));
                p2.u[r] = cvt_pk_bf16(__builtin_amdgcn_exp2f(s[8 + 2 * r]),
                                      __builtin_amdgcn_exp2f(s[8 + 2 * r + 1]));
            }
            acc = __builtin_amdgcn_mfma_f32_32x32x16_bf16(p1.v, vf1.v, acc, 0, 0, 0);
            acc = __builtin_amdgcn_mfma_f32_32x32x16_bf16(p2.v, vf2.v, acc, 0, 0, 0);
        }
        __builtin_amdgcn_s_setprio(0);
    }

    // inverse row-sums: output col 12 (ones row) at lane (lane&32)|12, same reg
    float invq[16];
#pragma unroll
    for (int r = 0; r < 16; ++r)
        invq[r] = 1.0f / __shfl(acc[r], (lane & 32) | 12);

    __syncthreads();   // all Ks/Vs reads done before Ot overwrites Ks
    // Ot per wave: [12 d][32 q] shorts at stride OT_STRIDE, block index = w
    {
        unsigned short* OtW = &Ks[0][0] + w * OT_STRIDE;
        if (q31 < HD) {
#pragma unroll
            for (int r2 = 0; r2 < 8; ++r2) {
                const int r = 2 * r2;
                const int q = (r & 3) + 8 * (r >> 2) + 4 * hi;
                const unsigned int dw = (unsigned int)f2bf(acc[r] * invq[r]) |
                                        ((unsigned int)f2bf(acc[r + 1] * invq[r + 1]) << 16);
                *reinterpret_cast<unsigned int*>(&OtW[q31 * 32 + q]) = dw;
            }
        }
    }
    __syncthreads();
    // store: 128 q, 256 threads: q = t>>1, half = t&1 covers d 0..5 / 6..11
    {
        const int q = t >> 1, half = t & 1;
        const unsigned short* Osrc = &Ks[0][0] + (q >> 5) * OT_STRIDE + (half * 6) * 32 + (q & 31);
        unsigned int dwv[3];
#pragma unroll
        for (int dp = 0; dp < 3; ++dp)
            dwv[dp] = (unsigned int)Osrc[(2 * dp) * 32] | ((unsigned int)Osrc[(2 * dp + 1) * 32] << 16);
        unsigned int* dst = reinterpret_cast<unsigned int*>(
            fused2 + ((size_t)b * HWN + n0 + q) * KTOT + coff + h * HD + half * 6);
#pragma unroll
        for (int dp = 0; dp < 3; ++dp) dst[dp] = dwv[dp];
    }
}

extern "C" void kernel_launch(void* const* d_in, const int* in_sizes, int n_in,
                              void* d_out, int out_size, void* d_ws, size_t ws_size,
                              hipStream_t stream) {
    (void)in_sizes; (void)n_in; (void)out_size; (void)ws_size;
    const float* x   = (const float*)d_in[0];
    const float* xbp = (const float*)d_in[1];
    const float* Wq  = (const float*)d_in[2];  const float* bq  = (const float*)d_in[3];
    const float* Wk  = (const float*)d_in[4];  const float* bk  = (const float*)d_in[5];
    const float* Wv  = (const float*)d_in[6];  const float* bv  = (const float*)d_in[7];
    const float* Wqb = (const float*)d_in[8];  const float* bqb = (const float*)d_in[9];
    const float* Wkb = (const float*)d_in[10]; const float* bkb = (const float*)d_in[11];
    const float* Wvb = (const float*)d_in[12]; const float* bvb = (const float*)d_in[13];
    const float* Wo  = (const float*)d_in[14]; const float* bo  = (const float*)d_in[15];
    float* out = (float*)d_out;

    char* ws = (char*)d_ws;
    size_t off = 0;
    auto alloc = [&](size_t bytes) -> void* {
        void* p = ws + off;
        off = (off + bytes + 255) & ~(size_t)255;
        return p;
    };
    unsigned short* wbf[6];
    for (int i = 0; i < 6; ++i) wbf[i] = (unsigned short*)alloc((size_t)EMBED * EMBED * 2);
    unsigned short* wo2 = (unsigned short*)alloc((size_t)HIDDEN * KTOT * 2);
    unsigned short* qkv[6];
    for (int i = 0; i < 6; ++i) qkv[i] = (unsigned short*)alloc((size_t)BB * EMBED * HWN * 2);
    unsigned short* fused2 = (unsigned short*)alloc((size_t)BB * HWN * KTOT * 2);

    // 1) weights -> bf16 (Wo duplicated into Wo2)
    WConv wc;
    const float* wsrc[7] = {Wq, Wk, Wv, Wqb, Wkb, Wvb, Wo};
    unsigned short* wdst[7] = {wbf[0], wbf[1], wbf[2], wbf[3], wbf[4], wbf[5], wo2};
    int acc4 = 0;
    for (int i = 0; i < 7; ++i) {
        const int n = (i < 6) ? EMBED * EMBED : HIDDEN * 768;
        wc.src[i] = wsrc[i];
        wc.dst[i] = wdst[i];
        wc.start[i] = acc4;
        acc4 += n / 4;
    }
    wc.start[7] = acc4;
    k_bf16_all<<<(acc4 + 255) / 256, 256, 0, stream>>>(wc);

    // 2) x, x_bpf -> token-major bf16 into fused2 cols 768..1535
    k_transpose<<<dim3(EMBED / 32, HWN / 32, 16), 256, 0, stream>>>(x, xbp, fused2);

    // 3) six QKV projections (128x128 tiles)
    QkvTable tab;
    tab.W[0] = wbf[0]; tab.W[1] = wbf[1]; tab.W[2] = wbf[2];
    tab.W[3] = wbf[3]; tab.W[4] = wbf[4]; tab.W[5] = wbf[5];
    tab.bias[0] = bq; tab.bias[1] = bk; tab.bias[2] = bv;
    tab.bias[3] = bqb; tab.bias[4] = bkb; tab.bias[5] = bvb;
    tab.fused2 = fused2;
    for (int i = 0; i < 6; ++i) tab.out[i] = qkv[i];
    k_gemm_qkv<<<dim3(EMBED / 128, HWN / 128, BB * 6), 256, 0, stream>>>(tab);

    // 4) MFMA attention -> fused2 cols 0..767 (512 instances x 8 q-tiles of 128, XCD-local)
    k_attn_mfma<<<dim3(4096), 256, 0, stream>>>(qkv[0], qkv[1], qkv[2], qkv[3], qkv[4], qkv[5],
                                                fused2);

    // 5) out = Wo2 . fused2 + bo   (K=1536 folds the residual)
    k_gemm_out<<<dim3(HIDDEN / 128, HWN / 128, BB), 256, 0, stream>>>(wo2, fused2, bo, out);
}

// Round 25
// 145.997 us; speedup vs baseline: 1.2171x; 1.0895x over previous
//
#include <hip/hip_runtime.h>
#include <hip/hip_bf16.h>

#define BB 8
#define EMBED 384
#define NH 32
#define HD 12
#define HWN 1024
#define HIDDEN 512
#define KTOT 1536
#define SCALE 0.28867513459481287f

typedef __attribute__((ext_vector_type(8))) unsigned short ushort8;
typedef __attribute__((ext_vector_type(8))) short short8;
typedef __attribute__((ext_vector_type(4))) float f32x4;
typedef __attribute__((ext_vector_type(16))) float f32x16;
typedef __attribute__((ext_vector_type(4))) unsigned short ushort4v;
typedef __attribute__((ext_vector_type(2))) unsigned int uint2v;

static __device__ __forceinline__ float bf2f(unsigned short u) {
    return __uint_as_float(((unsigned int)u) << 16);
}
static __device__ __forceinline__ unsigned short f2bf(float f) {
    unsigned int u = __float_as_uint(f);
    u = u + 0x7FFFu + ((u >> 16) & 1u);   // RNE
    return (unsigned short)(u >> 16);
}
static __device__ __forceinline__ unsigned int cvt_pk_bf16(float lo, float hi) {
    unsigned int r;
    asm("v_cvt_pk_bf16_f32 %0, %1, %2" : "=v"(r) : "v"(lo), "v"(hi));
    return r;
}

#if __has_builtin(__builtin_amdgcn_global_load_lds)
#define HAVE_GLOAD_LDS 1
static __device__ __forceinline__ void gl_lds16(const unsigned short* g, unsigned short* l) {
    __builtin_amdgcn_global_load_lds(
        (const __attribute__((address_space(1))) unsigned int*)g,
        (__attribute__((address_space(3))) unsigned int*)l, 16, 0, 0);
}
#else
#define HAVE_GLOAD_LDS 0
#endif

// ---------------- f32 -> bf16 weights; Wo duplicated into Wo2[512][1536] ----------------
struct WConv {
    const float* src[7];
    unsigned short* dst[7];
    int start[8];   // prefix over vec4 counts
};

__global__ __launch_bounds__(256) void k_bf16_all(WConv wc) {
    int i = blockIdx.x * 256 + threadIdx.x;
    if (i >= wc.start[7]) return;
    int p = 0;
#pragma unroll
    for (int j = 1; j < 7; ++j) p += (i >= wc.start[j]);
    const int e = i - wc.start[p];
    const f32x4 v = reinterpret_cast<const f32x4*>(wc.src[p])[e];
    ushort4v o;
#pragma unroll
    for (int j = 0; j < 4; ++j) o[j] = f2bf(v[j]);
    if (p == 6) {
        const int row = e / 192, cc = e % 192;
        ushort4v* d = reinterpret_cast<ushort4v*>(wc.dst[6]);
        d[row * 384 + cc] = o;
        d[row * 384 + 192 + cc] = o;
    } else {
        reinterpret_cast<ushort4v*>(wc.dst[p])[e] = o;
    }
}

// ---------------- transpose x (B,C,HW) f32 -> fused2[b][n][768 + s*384 + c] bf16 ----------------
__global__ __launch_bounds__(256) void k_transpose(const float* __restrict__ x0, const float* __restrict__ x1,
                                                   unsigned short* __restrict__ fused2) {
    __shared__ float tile[32][33];
    const int z = blockIdx.z;
    const int s = z >> 3, b = z & 7;
    const float* src = (s ? x1 : x0) + (size_t)b * EMBED * HWN;
    unsigned short* dst = fused2 + (size_t)b * HWN * KTOT + 768 + s * 384;
    const int c0 = blockIdx.x * 32;
    const int n0 = blockIdx.y * 32;
    const int tc = threadIdx.x & 31;
    const int tr = threadIdx.x >> 5;
#pragma unroll
    for (int p = 0; p < 4; ++p) {
        int r = tr + p * 8;
        tile[r][tc] = src[(size_t)(c0 + r) * HWN + n0 + tc];
    }
    __syncthreads();
#pragma unroll
    for (int p = 0; p < 4; ++p) {
        int r = tr + p * 8;
        dst[(size_t)(n0 + r) * KTOT + c0 + tc] = f2bf(tile[tc][r]);
    }
}

// ---------------- bf16 MFMA GEMM 128x128xBK64 + XOR swizzle (round-24 verified) ----------------
template <bool F32OUT>
static __device__ __forceinline__ void gemm128(const unsigned short* __restrict__ A, int lda,
                                               const unsigned short* __restrict__ Bt, int ldb,
                                               const float* __restrict__ bias,
                                               unsigned short* __restrict__ outBf,
                                               float* __restrict__ outF,
                                               int K, int bx, int by) {
    __shared__ unsigned short As[128][64];
    __shared__ unsigned short Bs[128][64];
    const int t = threadIdx.x;
    const int lane = t & 63;
    const int w = t >> 6;
    const int wr = w >> 1, wc = w & 1;
    const int o0 = bx * 128, n0 = by * 128;
    const int srow = lane >> 3;                              // 0..7 within chunk
    const int scol = (((lane & 7) ^ (lane >> 3)) << 3);      // swizzled source col (elements)

    f32x4 acc[4][4] = {};

    for (int k0 = 0; k0 < K; k0 += 64) {
#pragma unroll
        for (int i = 0; i < 4; ++i) {
            const int c = w * 4 + i;
            const int r = c * 8 + srow;
#if HAVE_GLOAD_LDS
            gl_lds16(A + (size_t)(o0 + r) * lda + k0 + scol, &As[c * 8][0]);
            gl_lds16(Bt + (size_t)(n0 + r) * ldb + k0 + scol, &Bs[c * 8][0]);
#else
            *reinterpret_cast<ushort8*>(&As[r][(lane & 7) * 8]) =
                *reinterpret_cast<const ushort8*>(A + (size_t)(o0 + r) * lda + k0 + scol);
            *reinterpret_cast<ushort8*>(&Bs[r][(lane & 7) * 8]) =
                *reinterpret_cast<const ushort8*>(Bt + (size_t)(n0 + r) * ldb + k0 + scol);
#endif
        }
        __syncthreads();
#pragma unroll
        for (int kk = 0; kk < 2; ++kk) {
            const int ko = kk * 32 + ((lane >> 4) << 3);
            const int xorb = (lane & 7) << 4;   // (R&7)<<4, R&7 == lane&7 for all frags
            short8 af[4], bf[4];
#pragma unroll
            for (int i = 0; i < 4; ++i) {
                const int ra = wr * 64 + i * 16 + (lane & 15);
                const int rb = wc * 64 + i * 16 + (lane & 15);
                af[i] = *reinterpret_cast<const short8*>(
                    reinterpret_cast<const char*>(&As[0][0]) + ra * 128 + ((ko * 2) ^ xorb));
                bf[i] = *reinterpret_cast<const short8*>(
                    reinterpret_cast<const char*>(&Bs[0][0]) + rb * 128 + ((ko * 2) ^ xorb));
            }
#pragma unroll
            for (int i = 0; i < 4; ++i)
#pragma unroll
                for (int j = 0; j < 4; ++j)
                    acc[i][j] = __builtin_amdgcn_mfma_f32_16x16x32_bf16(af[i], bf[j], acc[i][j], 0, 0, 0);
        }
        __syncthreads();
    }
#pragma unroll
    for (int i = 0; i < 4; ++i) {
#pragma unroll
        for (int j = 0; j < 4; ++j) {
            const int ob = o0 + wr * 64 + i * 16 + ((lane >> 4) << 2);
            const int n  = n0 + wc * 64 + j * 16 + (lane & 15);
#pragma unroll
            for (int r = 0; r < 4; ++r) {
                const int o = ob + r;
                float v = acc[i][j][r] + bias[o];
                if constexpr (F32OUT) outF[(size_t)o * HWN + n] = v;
                else                  outBf[(size_t)o * HWN + n] = f2bf(v);
            }
        }
    }
}

struct QkvTable {
    const unsigned short* W[6];
    const float* bias[6];
    const unsigned short* fused2;
    unsigned short* out[6];
};

__global__ __launch_bounds__(256) void k_gemm_qkv(QkvTable tab) {
    const int z = blockIdx.z;
    const int b = z / 6, p = z % 6;
    const unsigned short* Bt = tab.fused2 + (size_t)b * HWN * KTOT + 768 + (p / 3) * 384;
    gemm128<false>(tab.W[p], EMBED, Bt, KTOT, tab.bias[p],
                   tab.out[p] + (size_t)b * EMBED * HWN, nullptr,
                   EMBED, blockIdx.x, blockIdx.y);
}

__global__ __launch_bounds__(256) void k_gemm_out(const unsigned short* __restrict__ Wo2,
                                                  const unsigned short* __restrict__ fused2,
                                                  const float* __restrict__ bo,
                                                  float* __restrict__ out) {
    const int b = blockIdx.z;
    gemm128<true>(Wo2, KTOT, fused2 + (size_t)b * HWN * KTOT, KTOT, bo,
                  nullptr, out + (size_t)b * HIDDEN * HWN,
                  KTOT, blockIdx.x, blockIdx.y);
}

// ---------------- MFMA flash attention v11: 256 q/block, 8 waves, 1 frag/wave ----------------
// Combines v8's staging amortization (256 q share one K/V stage) with v10's low VGPR (1 frag).
// 8-wave blocks: 4 blocks/CU = 32 waves/CU theoretical. Staging split across 8 waves:
// waves 0-5 own K d-dword col w (stride-9-dword writes, conflict-free) + V rows 2w,2w+1;
// waves 6/7 zero-fill K cols 12-15; wave 6 lanes<32 write the ones V-row.
#define OT_STRIDE 416
__global__ __launch_bounds__(512) void k_attn_mfma(const unsigned short* __restrict__ qc,
                                                   const unsigned short* __restrict__ kc,
                                                   const unsigned short* __restrict__ vc,
                                                   const unsigned short* __restrict__ qcb,
                                                   const unsigned short* __restrict__ kcb,
                                                   const unsigned short* __restrict__ vcb,
                                                   unsigned short* __restrict__ fused2) {
    __shared__ unsigned short Ks[256][18];   // [m][d 0..15 + 2 pad], 36B rows (9 dw, coprime 32)
    __shared__ unsigned short Vs[13][264];   // [d][m], row 12 = ones

    const int bid = blockIdx.x;
    const int inst = bid & 511, qt = bid >> 9;      // blocks sharing inst are 512 apart -> same XCD
    const int branch = inst >> 8, b = (inst >> 5) & 7, h = inst & 31;
    const unsigned short* Qg = branch ? qc : qcb;
    const unsigned short* Kg = branch ? kcb : kc;
    const unsigned short* Vg = branch ? vcb : vc;
    const int coff = branch ? 384 : 0;
    const size_t base = ((size_t)b * EMBED + h * HD) * HWN;
    const int t = threadIdx.x;
    const int lane = t & 63, w = t >> 6;            // w = 0..7
    const int q31 = lane & 31, hi = lane >> 5;
    const int n0 = qt * 256;
    const float C2 = SCALE * 1.4426950408889634f;

    // Q B-frag (32x32x16): lane (q31,hi) holds Q[d=hi*8+j][q = n0 + w*32 + q31], pre-scaled by C2
    short8 qf = {};
    {
        const int qg = n0 + w * 32 + q31;
#pragma unroll
        for (int j = 0; j < 8; ++j) {
            const int d = hi * 8 + j;
            if (d < HD)
                qf[j] = (short)f2bf(bf2f(Qg[base + (size_t)d * HWN + qg]) * C2);
        }
    }

    f32x16 acc, z16;
#pragma unroll
    for (int r = 0; r < 16; ++r) { acc[r] = 0.f; z16[r] = 0.f; }
    const int vrow = (q31 < HD) ? q31 : 12;   // lanes d>=12 read ones row (outputs discarded)

    for (int phase = 0; phase < 4; ++phase) {
        const int m0 = phase << 8;
        __syncthreads();   // prior-phase reads done
        // --- stage K (256 m): waves 0-5 own d-pair (2w, 2w+1) -> dword col w; waves 6/7 zero cols 12-15
        if (w < 6) {
            const size_t kb = base + (size_t)(2 * w) * HWN + m0;
#pragma unroll
            for (int it = 0; it < 4; ++it) {
                const int m = it * 64 + lane;
                const unsigned int da = (unsigned int)Kg[kb + m] | ((unsigned int)Kg[kb + HWN + m] << 16);
                reinterpret_cast<unsigned int*>(&Ks[m][0])[m * 8 + w] = da;   // &Ks[m][2w] as dword: m*9+w... see below
            }
        }
        // NOTE: the line above must compute dword index m*9 + w (Ks row = 9 dwords). Rewritten correctly:
        if (w < 6) {
            const size_t kb = base + (size_t)(2 * w) * HWN + m0;
#pragma unroll
            for (int it = 0; it < 4; ++it) {
                const int m = it * 64 + lane;
                const unsigned int da = (unsigned int)Kg[kb + m] | ((unsigned int)Kg[kb + HWN + m] << 16);
                *reinterpret_cast<unsigned int*>(&Ks[m][2 * w]) = da;
            }
        } else {
            const int cz = 12 + 2 * (w - 6);   // cols 12-13 (w=6) / 14-15 (w=7)
#pragma unroll
            for (int it = 0; it < 4; ++it) {
                const int m = it * 64 + lane;
                *reinterpret_cast<unsigned int*>(&Ks[m][cz]) = 0u;
            }
        }
        // --- stage V (256 m): waves 0-5 own V rows 2w + (lane>>5); wave 6 lanes<32 write ones row
        if (w < 6) {
            const int d = 2 * w + (lane >> 5);
            const int col = (lane & 31) * 8;
            *reinterpret_cast<ushort8*>(&Vs[d][col]) =
                *reinterpret_cast<const ushort8*>(&Vg[base + (size_t)d * HWN + m0 + col]);
        } else if (w == 6 && lane < 32) {
            ushort8 ones;
#pragma unroll
            for (int j = 0; j < 8; ++j) ones[j] = 0x3F80;
            *reinterpret_cast<ushort8*>(&Vs[12][lane * 8]) = ones;
        }
        __syncthreads();

        __builtin_amdgcn_s_setprio(1);
        for (int mc = 0; mc < 8; ++mc) {
            const int mb = mc << 5;
            // K A-frag: lane (m-local = q31, hi) = K[mb+q31][d = hi*8+j]; dword loads (36B rows)
            union { short8 v; unsigned int u[4]; } kf;
            {
                const unsigned int* kp = reinterpret_cast<const unsigned int*>(&Ks[mb + q31][hi * 8]);
                kf.u[0] = kp[0]; kf.u[1] = kp[1]; kf.u[2] = kp[2]; kf.u[3] = kp[3];
            }
            // V B-frags, sigma-permuted k-rows: PV1 m {0..3,8..11}+4hi, PV2 +16
            union { short8 v; uint2v u2[2]; } vf1, vf2;
            vf1.u2[0] = *reinterpret_cast<const uint2v*>(&Vs[vrow][mb + hi * 4]);
            vf1.u2[1] = *reinterpret_cast<const uint2v*>(&Vs[vrow][mb + 8 + hi * 4]);
            vf2.u2[0] = *reinterpret_cast<const uint2v*>(&Vs[vrow][mb + 16 + hi * 4]);
            vf2.u2[1] = *reinterpret_cast<const uint2v*>(&Vs[vrow][mb + 24 + hi * 4]);
            // QKT: C reg r = P[m=(r&3)+8*(r>>2)+4hi][q=q31]
            const f32x16 s = __builtin_amdgcn_mfma_f32_32x32x16_bf16(kf.v, qf, z16, 0, 0, 0);
            union { short8 v; unsigned int u[4]; } p1, p2;
#pragma unroll
            for (int r = 0; r < 4; ++r) {
                p1.u[r] = cvt_pk_bf16(__builtin_amdgcn_exp2f(s[2 * r]),
                                      __builtin_amdgcn_exp2f(s[2 * r + 1]));
                p2.u[r] = cvt_pk_bf16(__builtin_amdgcn_exp2f(s[8 + 2 * r]),
                                      __builtin_amdgcn_exp2f(s[8 + 2 * r + 1]));
            }
            acc = __builtin_amdgcn_mfma_f32_32x32x16_bf16(p1.v, vf1.v, acc, 0, 0, 0);
            acc = __builtin_amdgcn_mfma_f32_32x32x16_bf16(p2.v, vf2.v, acc, 0, 0, 0);
        }
        __builtin_amdgcn_s_setprio(0);
    }

    // inverse row-sums: output col 12 (ones row) at lane (lane&32)|12, same reg
    float invq[16];
#pragma unroll
    for (int r = 0; r < 16; ++r)
        invq[r] = 1.0f / __shfl(acc[r], (lane & 32) | 12);

    __syncthreads();   // all Ks/Vs reads done before Ot overwrites Ks
    // Ot per wave: [12 d][32 q] shorts at stride OT_STRIDE, block index = w (0..7)
    {
        unsigned short* OtW = &Ks[0][0] + w * OT_STRIDE;
        if (q31 < HD) {
#pragma unroll
            for (int r2 = 0; r2 < 8; ++r2) {
                const int r = 2 * r2;
                const int q = (r & 3) + 8 * (r >> 2) + 4 * hi;
                const unsigned int dw = (unsigned int)f2bf(acc[r] * invq[r]) |
                                        ((unsigned int)f2bf(acc[r + 1] * invq[r + 1]) << 16);
                *reinterpret_cast<unsigned int*>(&OtW[q31 * 32 + q]) = dw;
            }
        }
    }
    __syncthreads();
    // store: 256 q, 512 threads: q = t>>1, half = t&1 covers d 0..5 / 6..11
    {
        const int q = t >> 1, half = t & 1;
        const unsigned short* Osrc = &Ks[0][0] + (q >> 5) * OT_STRIDE + (half * 6) * 32 + (q & 31);
        unsigned int dwv[3];
#pragma unroll
        for (int dp = 0; dp < 3; ++dp)
            dwv[dp] = (unsigned int)Osrc[(2 * dp) * 32] | ((unsigned int)Osrc[(2 * dp + 1) * 32] << 16);
        unsigned int* dst = reinterpret_cast<unsigned int*>(
            fused2 + ((size_t)b * HWN + n0 + q) * KTOT + coff + h * HD + half * 6);
#pragma unroll
        for (int dp = 0; dp < 3; ++dp) dst[dp] = dwv[dp];
    }
}

extern "C" void kernel_launch(void* const* d_in, const int* in_sizes, int n_in,
                              void* d_out, int out_size, void* d_ws, size_t ws_size,
                              hipStream_t stream) {
    (void)in_sizes; (void)n_in; (void)out_size; (void)ws_size;
    const float* x   = (const float*)d_in[0];
    const float* xbp = (const float*)d_in[1];
    const float* Wq  = (const float*)d_in[2];  const float* bq  = (const float*)d_in[3];
    const float* Wk  = (const float*)d_in[4];  const float* bk  = (const float*)d_in[5];
    const float* Wv  = (const float*)d_in[6];  const float* bv  = (const float*)d_in[7];
    const float* Wqb = (const float*)d_in[8];  const float* bqb = (const float*)d_in[9];
    const float* Wkb = (const float*)d_in[10]; const float* bkb = (const float*)d_in[11];
    const float* Wvb = (const float*)d_in[12]; const float* bvb = (const float*)d_in[13];
    const float* Wo  = (const float*)d_in[14]; const float* bo  = (const float*)d_in[15];
    float* out = (float*)d_out;

    char* ws = (char*)d_ws;
    size_t off = 0;
    auto alloc = [&](size_t bytes) -> void* {
        void* p = ws + off;
        off = (off + bytes + 255) & ~(size_t)255;
        return p;
    };
    unsigned short* wbf[6];
    for (int i = 0; i < 6; ++i) wbf[i] = (unsigned short*)alloc((size_t)EMBED * EMBED * 2);
    unsigned short* wo2 = (unsigned short*)alloc((size_t)HIDDEN * KTOT * 2);
    unsigned short* qkv[6];
    for (int i = 0; i < 6; ++i) qkv[i] = (unsigned short*)alloc((size_t)BB * EMBED * HWN * 2);
    unsigned short* fused2 = (unsigned short*)alloc((size_t)BB * HWN * KTOT * 2);

    // 1) weights -> bf16 (Wo duplicated into Wo2)
    WConv wc;
    const float* wsrc[7] = {Wq, Wk, Wv, Wqb, Wkb, Wvb, Wo};
    unsigned short* wdst[7] = {wbf[0], wbf[1], wbf[2], wbf[3], wbf[4], wbf[5], wo2};
    int acc4 = 0;
    for (int i = 0; i < 7; ++i) {
        const int n = (i < 6) ? EMBED * EMBED : HIDDEN * 768;
        wc.src[i] = wsrc[i];
        wc.dst[i] = wdst[i];
        wc.start[i] = acc4;
        acc4 += n / 4;
    }
    wc.start[7] = acc4;
    k_bf16_all<<<(acc4 + 255) / 256, 256, 0, stream>>>(wc);

    // 2) x, x_bpf -> token-major bf16 into fused2 cols 768..1535
    k_transpose<<<dim3(EMBED / 32, HWN / 32, 16), 256, 0, stream>>>(x, xbp, fused2);

    // 3) six QKV projections (128x128 tiles)
    QkvTable tab;
    tab.W[0] = wbf[0]; tab.W[1] = wbf[1]; tab.W[2] = wbf[2];
    tab.W[3] = wbf[3]; tab.W[4] = wbf[4]; tab.W[5] = wbf[5];
    tab.bias[0] = bq; tab.bias[1] = bk; tab.bias[2] = bv;
    tab.bias[3] = bqb; tab.bias[4] = bkb; tab.bias[5] = bvb;
    tab.fused2 = fused2;
    for (int i = 0; i < 6; ++i) tab.out[i] = qkv[i];
    k_gemm_qkv<<<dim3(EMBED / 128, HWN / 128, BB * 6), 256, 0, stream>>>(tab);

    // 4) MFMA attention -> fused2 cols 0..767 (512 instances x 4 q-tiles of 256, 8-wave blocks)
    k_attn_mfma<<<dim3(2048), 512, 0, stream>>>(qkv[0], qkv[1], qkv[2], qkv[3], qkv[4], qkv[5],
                                                fused2);

    // 5) out = Wo2 . fused2 + bo   (K=1536 folds the residual)
    k_gemm_out<<<dim3(HIDDEN / 128, HWN / 128, BB), 256, 0, stream>>>(wo2, fused2, bo, out);
}

// Round 26
// 144.732 us; speedup vs baseline: 1.2278x; 1.0087x over previous
//
#include <hip/hip_runtime.h>
#include <hip/hip_bf16.h>

#define BB 8
#define EMBED 384
#define NH 32
#define HD 12
#define HWN 1024
#define HIDDEN 512
#define KTOT 1536
#define SCALE 0.28867513459481287f

typedef __attribute__((ext_vector_type(8))) unsigned short ushort8;
typedef __attribute__((ext_vector_type(8))) short short8;
typedef __attribute__((ext_vector_type(4))) float f32x4;
typedef __attribute__((ext_vector_type(16))) float f32x16;
typedef __attribute__((ext_vector_type(4))) unsigned short ushort4v;
typedef __attribute__((ext_vector_type(2))) unsigned int uint2v;

static __device__ __forceinline__ float bf2f(unsigned short u) {
    return __uint_as_float(((unsigned int)u) << 16);
}
static __device__ __forceinline__ unsigned short f2bf(float f) {
    unsigned int u = __float_as_uint(f);
    u = u + 0x7FFFu + ((u >> 16) & 1u);   // RNE
    return (unsigned short)(u >> 16);
}
static __device__ __forceinline__ unsigned int cvt_pk_bf16(float lo, float hi) {
    unsigned int r;
    asm("v_cvt_pk_bf16_f32 %0, %1, %2" : "=v"(r) : "v"(lo), "v"(hi));
    return r;
}

#if __has_builtin(__builtin_amdgcn_global_load_lds)
#define HAVE_GLOAD_LDS 1
static __device__ __forceinline__ void gl_lds16(const unsigned short* g, unsigned short* l) {
    __builtin_amdgcn_global_load_lds(
        (const __attribute__((address_space(1))) unsigned int*)g,
        (__attribute__((address_space(3))) unsigned int*)l, 16, 0, 0);
}
#else
#define HAVE_GLOAD_LDS 0
#endif

// ---------------- f32 -> bf16 weights; Wo duplicated into Wo2[512][1536] ----------------
struct WConv {
    const float* src[7];
    unsigned short* dst[7];
    int start[8];   // prefix over vec4 counts
};

__global__ __launch_bounds__(256) void k_bf16_all(WConv wc) {
    int i = blockIdx.x * 256 + threadIdx.x;
    if (i >= wc.start[7]) return;
    int p = 0;
#pragma unroll
    for (int j = 1; j < 7; ++j) p += (i >= wc.start[j]);
    const int e = i - wc.start[p];
    const f32x4 v = reinterpret_cast<const f32x4*>(wc.src[p])[e];
    ushort4v o;
#pragma unroll
    for (int j = 0; j < 4; ++j) o[j] = f2bf(v[j]);
    if (p == 6) {
        const int row = e / 192, cc = e % 192;
        ushort4v* d = reinterpret_cast<ushort4v*>(wc.dst[6]);
        d[row * 384 + cc] = o;
        d[row * 384 + 192 + cc] = o;
    } else {
        reinterpret_cast<ushort4v*>(wc.dst[p])[e] = o;
    }
}

// ---------------- transpose x (B,C,HW) f32 -> fused2[b][n][768 + s*384 + c] bf16 ----------------
__global__ __launch_bounds__(256) void k_transpose(const float* __restrict__ x0, const float* __restrict__ x1,
                                                   unsigned short* __restrict__ fused2) {
    __shared__ float tile[32][33];
    const int z = blockIdx.z;
    const int s = z >> 3, b = z & 7;
    const float* src = (s ? x1 : x0) + (size_t)b * EMBED * HWN;
    unsigned short* dst = fused2 + (size_t)b * HWN * KTOT + 768 + s * 384;
    const int c0 = blockIdx.x * 32;
    const int n0 = blockIdx.y * 32;
    const int tc = threadIdx.x & 31;
    const int tr = threadIdx.x >> 5;
#pragma unroll
    for (int p = 0; p < 4; ++p) {
        int r = tr + p * 8;
        tile[r][tc] = src[(size_t)(c0 + r) * HWN + n0 + tc];
    }
    __syncthreads();
#pragma unroll
    for (int p = 0; p < 4; ++p) {
        int r = tr + p * 8;
        dst[(size_t)(n0 + r) * KTOT + c0 + tc] = f2bf(tile[tc][r]);
    }
}

// ---------------- bf16 MFMA GEMM 128x128xBK64 + XOR swizzle (round-24 verified) ----------------
template <bool F32OUT>
static __device__ __forceinline__ void gemm128(const unsigned short* __restrict__ A, int lda,
                                               const unsigned short* __restrict__ Bt, int ldb,
                                               const float* __restrict__ bias,
                                               unsigned short* __restrict__ outBf,
                                               float* __restrict__ outF,
                                               int K, int bx, int by) {
    __shared__ unsigned short As[128][64];
    __shared__ unsigned short Bs[128][64];
    const int t = threadIdx.x;
    const int lane = t & 63;
    const int w = t >> 6;
    const int wr = w >> 1, wc = w & 1;
    const int o0 = bx * 128, n0 = by * 128;
    const int srow = lane >> 3;                              // 0..7 within chunk
    const int scol = (((lane & 7) ^ (lane >> 3)) << 3);      // swizzled source col (elements)

    f32x4 acc[4][4] = {};

    for (int k0 = 0; k0 < K; k0 += 64) {
#pragma unroll
        for (int i = 0; i < 4; ++i) {
            const int c = w * 4 + i;
            const int r = c * 8 + srow;
#if HAVE_GLOAD_LDS
            gl_lds16(A + (size_t)(o0 + r) * lda + k0 + scol, &As[c * 8][0]);
            gl_lds16(Bt + (size_t)(n0 + r) * ldb + k0 + scol, &Bs[c * 8][0]);
#else
            *reinterpret_cast<ushort8*>(&As[r][(lane & 7) * 8]) =
                *reinterpret_cast<const ushort8*>(A + (size_t)(o0 + r) * lda + k0 + scol);
            *reinterpret_cast<ushort8*>(&Bs[r][(lane & 7) * 8]) =
                *reinterpret_cast<const ushort8*>(Bt + (size_t)(n0 + r) * ldb + k0 + scol);
#endif
        }
        __syncthreads();
#pragma unroll
        for (int kk = 0; kk < 2; ++kk) {
            const int ko = kk * 32 + ((lane >> 4) << 3);
            const int xorb = (lane & 7) << 4;   // (R&7)<<4, R&7 == lane&7 for all frags
            short8 af[4], bf[4];
#pragma unroll
            for (int i = 0; i < 4; ++i) {
                const int ra = wr * 64 + i * 16 + (lane & 15);
                const int rb = wc * 64 + i * 16 + (lane & 15);
                af[i] = *reinterpret_cast<const short8*>(
                    reinterpret_cast<const char*>(&As[0][0]) + ra * 128 + ((ko * 2) ^ xorb));
                bf[i] = *reinterpret_cast<const short8*>(
                    reinterpret_cast<const char*>(&Bs[0][0]) + rb * 128 + ((ko * 2) ^ xorb));
            }
#pragma unroll
            for (int i = 0; i < 4; ++i)
#pragma unroll
                for (int j = 0; j < 4; ++j)
                    acc[i][j] = __builtin_amdgcn_mfma_f32_16x16x32_bf16(af[i], bf[j], acc[i][j], 0, 0, 0);
        }
        __syncthreads();
    }
#pragma unroll
    for (int i = 0; i < 4; ++i) {
#pragma unroll
        for (int j = 0; j < 4; ++j) {
            const int ob = o0 + wr * 64 + i * 16 + ((lane >> 4) << 2);
            const int n  = n0 + wc * 64 + j * 16 + (lane & 15);
#pragma unroll
            for (int r = 0; r < 4; ++r) {
                const int o = ob + r;
                float v = acc[i][j][r] + bias[o];
                if constexpr (F32OUT) outF[(size_t)o * HWN + n] = v;
                else                  outBf[(size_t)o * HWN + n] = f2bf(v);
            }
        }
    }
}

struct QkvTable {
    const unsigned short* W[6];
    const float* bias[6];
    const unsigned short* fused2;
    unsigned short* out[6];
};

__global__ __launch_bounds__(256) void k_gemm_qkv(QkvTable tab) {
    const int z = blockIdx.z;
    const int b = z / 6, p = z % 6;
    const unsigned short* Bt = tab.fused2 + (size_t)b * HWN * KTOT + 768 + (p / 3) * 384;
    gemm128<false>(tab.W[p], EMBED, Bt, KTOT, tab.bias[p],
                   tab.out[p] + (size_t)b * EMBED * HWN, nullptr,
                   EMBED, blockIdx.x, blockIdx.y);
}

__global__ __launch_bounds__(256) void k_gemm_out(const unsigned short* __restrict__ Wo2,
                                                  const unsigned short* __restrict__ fused2,
                                                  const float* __restrict__ bo,
                                                  float* __restrict__ out) {
    const int b = blockIdx.z;
    gemm128<true>(Wo2, KTOT, fused2 + (size_t)b * HWN * KTOT, KTOT, bo,
                  nullptr, out + (size_t)b * HIDDEN * HWN,
                  KTOT, blockIdx.x, blockIdx.y);
}

// ---------------- MFMA flash attention v11.1: 256 q/block, 8 waves, 1 frag/wave ----------------
// v11 with the duplicated/buggy K-staging block REMOVED (it raced with the correct writes and
// scattered dwords outside Ks -- the absmax 0.0156->0.0352 regression). Single correct staging:
// waves 0-5 own K d-pair (2w,2w+1) -> dword col w (stride-9-dw, conflict-free) + V row pair;
// waves 6/7 zero K cols 12-15; wave 6 lanes<32 write the ones V-row.
#define OT_STRIDE 416
__global__ __launch_bounds__(512) void k_attn_mfma(const unsigned short* __restrict__ qc,
                                                   const unsigned short* __restrict__ kc,
                                                   const unsigned short* __restrict__ vc,
                                                   const unsigned short* __restrict__ qcb,
                                                   const unsigned short* __restrict__ kcb,
                                                   const unsigned short* __restrict__ vcb,
                                                   unsigned short* __restrict__ fused2) {
    __shared__ unsigned short Ks[256][18];   // [m][d 0..15 + 2 pad], 36B rows (9 dw, coprime 32)
    __shared__ unsigned short Vs[13][264];   // [d][m], row 12 = ones

    const int bid = blockIdx.x;
    const int inst = bid & 511, qt = bid >> 9;      // blocks sharing inst are 512 apart -> same XCD
    const int branch = inst >> 8, b = (inst >> 5) & 7, h = inst & 31;
    const unsigned short* Qg = branch ? qc : qcb;
    const unsigned short* Kg = branch ? kcb : kc;
    const unsigned short* Vg = branch ? vcb : vc;
    const int coff = branch ? 384 : 0;
    const size_t base = ((size_t)b * EMBED + h * HD) * HWN;
    const int t = threadIdx.x;
    const int lane = t & 63, w = t >> 6;            // w = 0..7
    const int q31 = lane & 31, hi = lane >> 5;
    const int n0 = qt * 256;
    const float C2 = SCALE * 1.4426950408889634f;

    // Q B-frag (32x32x16): lane (q31,hi) holds Q[d=hi*8+j][q = n0 + w*32 + q31], pre-scaled by C2
    short8 qf = {};
    {
        const int qg = n0 + w * 32 + q31;
#pragma unroll
        for (int j = 0; j < 8; ++j) {
            const int d = hi * 8 + j;
            if (d < HD)
                qf[j] = (short)f2bf(bf2f(Qg[base + (size_t)d * HWN + qg]) * C2);
        }
    }

    f32x16 acc, z16;
#pragma unroll
    for (int r = 0; r < 16; ++r) { acc[r] = 0.f; z16[r] = 0.f; }
    const int vrow = (q31 < HD) ? q31 : 12;   // lanes d>=12 read ones row (outputs discarded)

    for (int phase = 0; phase < 4; ++phase) {
        const int m0 = phase << 8;
        __syncthreads();   // prior-phase reads done
        // --- stage K (256 m): waves 0-5 own d-pair (2w, 2w+1) -> dword col w; waves 6/7 zero cols 12-15
        if (w < 6) {
            const size_t kb = base + (size_t)(2 * w) * HWN + m0;
#pragma unroll
            for (int it = 0; it < 4; ++it) {
                const int m = it * 64 + lane;
                const unsigned int da = (unsigned int)Kg[kb + m] | ((unsigned int)Kg[kb + HWN + m] << 16);
                *reinterpret_cast<unsigned int*>(&Ks[m][2 * w]) = da;
            }
        } else {
            const int cz = 12 + 2 * (w - 6);   // cols 12-13 (w=6) / 14-15 (w=7)
#pragma unroll
            for (int it = 0; it < 4; ++it) {
                const int m = it * 64 + lane;
                *reinterpret_cast<unsigned int*>(&Ks[m][cz]) = 0u;
            }
        }
        // --- stage V (256 m): waves 0-5 own V rows 2w + (lane>>5); wave 6 lanes<32 write ones row
        if (w < 6) {
            const int d = 2 * w + (lane >> 5);
            const int col = (lane & 31) * 8;
            *reinterpret_cast<ushort8*>(&Vs[d][col]) =
                *reinterpret_cast<const ushort8*>(&Vg[base + (size_t)d * HWN + m0 + col]);
        } else if (w == 6 && lane < 32) {
            ushort8 ones;
#pragma unroll
            for (int j = 0; j < 8; ++j) ones[j] = 0x3F80;
            *reinterpret_cast<ushort8*>(&Vs[12][lane * 8]) = ones;
        }
        __syncthreads();

        __builtin_amdgcn_s_setprio(1);
        for (int mc = 0; mc < 8; ++mc) {
            const int mb = mc << 5;
            // K A-frag: lane (m-local = q31, hi) = K[mb+q31][d = hi*8+j]; dword loads (36B rows)
            union { short8 v; unsigned int u[4]; } kf;
            {
                const unsigned int* kp = reinterpret_cast<const unsigned int*>(&Ks[mb + q31][hi * 8]);
                kf.u[0] = kp[0]; kf.u[1] = kp[1]; kf.u[2] = kp[2]; kf.u[3] = kp[3];
            }
            // V B-frags, sigma-permuted k-rows: PV1 m {0..3,8..11}+4hi, PV2 +16
            union { short8 v; uint2v u2[2]; } vf1, vf2;
            vf1.u2[0] = *reinterpret_cast<const uint2v*>(&Vs[vrow][mb + hi * 4]);
            vf1.u2[1] = *reinterpret_cast<const uint2v*>(&Vs[vrow][mb + 8 + hi * 4]);
            vf2.u2[0] = *reinterpret_cast<const uint2v*>(&Vs[vrow][mb + 16 + hi * 4]);
            vf2.u2[1] = *reinterpret_cast<const uint2v*>(&Vs[vrow][mb + 24 + hi * 4]);
            // QKT: C reg r = P[m=(r&3)+8*(r>>2)+4hi][q=q31]
            const f32x16 s = __builtin_amdgcn_mfma_f32_32x32x16_bf16(kf.v, qf, z16, 0, 0, 0);
            union { short8 v; unsigned int u[4]; } p1, p2;
#pragma unroll
            for (int r = 0; r < 4; ++r) {
                p1.u[r] = cvt_pk_bf16(__builtin_amdgcn_exp2f(s[2 * r]),
                                      __builtin_amdgcn_exp2f(s[2 * r + 1]));
                p2.u[r] = cvt_pk_bf16(__builtin_amdgcn_exp2f(s[8 + 2 * r]),
                                      __builtin_amdgcn_exp2f(s[8 + 2 * r + 1]));
            }
            acc = __builtin_amdgcn_mfma_f32_32x32x16_bf16(p1.v, vf1.v, acc, 0, 0, 0);
            acc = __builtin_amdgcn_mfma_f32_32x32x16_bf16(p2.v, vf2.v, acc, 0, 0, 0);
        }
        __builtin_amdgcn_s_setprio(0);
    }

    // inverse row-sums: output col 12 (ones row) at lane (lane&32)|12, same reg
    float invq[16];
#pragma unroll
    for (int r = 0; r < 16; ++r)
        invq[r] = 1.0f / __shfl(acc[r], (lane & 32) | 12);

    __syncthreads();   // all Ks/Vs reads done before Ot overwrites Ks
    // Ot per wave: [12 d][32 q] shorts at stride OT_STRIDE, block index = w (0..7)
    {
        unsigned short* OtW = &Ks[0][0] + w * OT_STRIDE;
        if (q31 < HD) {
#pragma unroll
            for (int r2 = 0; r2 < 8; ++r2) {
                const int r = 2 * r2;
                const int q = (r & 3) + 8 * (r >> 2) + 4 * hi;
                const unsigned int dw = (unsigned int)f2bf(acc[r] * invq[r]) |
                                        ((unsigned int)f2bf(acc[r + 1] * invq[r + 1]) << 16);
                *reinterpret_cast<unsigned int*>(&OtW[q31 * 32 + q]) = dw;
            }
        }
    }
    __syncthreads();
    // store: 256 q, 512 threads: q = t>>1, half = t&1 covers d 0..5 / 6..11
    {
        const int q = t >> 1, half = t & 1;
        const unsigned short* Osrc = &Ks[0][0] + (q >> 5) * OT_STRIDE + (half * 6) * 32 + (q & 31);
        unsigned int dwv[3];
#pragma unroll
        for (int dp = 0; dp < 3; ++dp)
            dwv[dp] = (unsigned int)Osrc[(2 * dp) * 32] | ((unsigned int)Osrc[(2 * dp + 1) * 32] << 16);
        unsigned int* dst = reinterpret_cast<unsigned int*>(
            fused2 + ((size_t)b * HWN + n0 + q) * KTOT + coff + h * HD + half * 6);
#pragma unroll
        for (int dp = 0; dp < 3; ++dp) dst[dp] = dwv[dp];
    }
}

extern "C" void kernel_launch(void* const* d_in, const int* in_sizes, int n_in,
                              void* d_out, int out_size, void* d_ws, size_t ws_size,
                              hipStream_t stream) {
    (void)in_sizes; (void)n_in; (void)out_size; (void)ws_size;
    const float* x   = (const float*)d_in[0];
    const float* xbp = (const float*)d_in[1];
    const float* Wq  = (const float*)d_in[2];  const float* bq  = (const float*)d_in[3];
    const float* Wk  = (const float*)d_in[4];  const float* bk  = (const float*)d_in[5];
    const float* Wv  = (const float*)d_in[6];  const float* bv  = (const float*)d_in[7];
    const float* Wqb = (const float*)d_in[8];  const float* bqb = (const float*)d_in[9];
    const float* Wkb = (const float*)d_in[10]; const float* bkb = (const float*)d_in[11];
    const float* Wvb = (const float*)d_in[12]; const float* bvb = (const float*)d_in[13];
    const float* Wo  = (const float*)d_in[14]; const float* bo  = (const float*)d_in[15];
    float* out = (float*)d_out;

    char* ws = (char*)d_ws;
    size_t off = 0;
    auto alloc = [&](size_t bytes) -> void* {
        void* p = ws + off;
        off = (off + bytes + 255) & ~(size_t)255;
        return p;
    };
    unsigned short* wbf[6];
    for (int i = 0; i < 6; ++i) wbf[i] = (unsigned short*)alloc((size_t)EMBED * EMBED * 2);
    unsigned short* wo2 = (unsigned short*)alloc((size_t)HIDDEN * KTOT * 2);
    unsigned short* qkv[6];
    for (int i = 0; i < 6; ++i) qkv[i] = (unsigned short*)alloc((size_t)BB * EMBED * HWN * 2);
    unsigned short* fused2 = (unsigned short*)alloc((size_t)BB * HWN * KTOT * 2);

    // 1) weights -> bf16 (Wo duplicated into Wo2)
    WConv wc;
    const float* wsrc[7] = {Wq, Wk, Wv, Wqb, Wkb, Wvb, Wo};
    unsigned short* wdst[7] = {wbf[0], wbf[1], wbf[2], wbf[3], wbf[4], wbf[5], wo2};
    int acc4 = 0;
    for (int i = 0; i < 7; ++i) {
        const int n = (i < 6) ? EMBED * EMBED : HIDDEN * 768;
        wc.src[i] = wsrc[i];
        wc.dst[i] = wdst[i];
        wc.start[i] = acc4;
        acc4 += n / 4;
    }
    wc.start[7] = acc4;
    k_bf16_all<<<(acc4 + 255) / 256, 256, 0, stream>>>(wc);

    // 2) x, x_bpf -> token-major bf16 into fused2 cols 768..1535
    k_transpose<<<dim3(EMBED / 32, HWN / 32, 16), 256, 0, stream>>>(x, xbp, fused2);

    // 3) six QKV projections (128x128 tiles)
    QkvTable tab;
    tab.W[0] = wbf[0]; tab.W[1] = wbf[1]; tab.W[2] = wbf[2];
    tab.W[3] = wbf[3]; tab.W[4] = wbf[4]; tab.W[5] = wbf[5];
    tab.bias[0] = bq; tab.bias[1] = bk; tab.bias[2] = bv;
    tab.bias[3] = bqb; tab.bias[4] = bkb; tab.bias[5] = bvb;
    tab.fused2 = fused2;
    for (int i = 0; i < 6; ++i) tab.out[i] = qkv[i];
    k_gemm_qkv<<<dim3(EMBED / 128, HWN / 128, BB * 6), 256, 0, stream>>>(tab);

    // 4) MFMA attention -> fused2 cols 0..767 (512 instances x 4 q-tiles of 256, 8-wave blocks)
    k_attn_mfma<<<dim3(2048), 512, 0, stream>>>(qkv[0], qkv[1], qkv[2], qkv[3], qkv[4], qkv[5],
                                                fused2);

    // 5) out = Wo2 . fused2 + bo   (K=1536 folds the residual)
    k_gemm_out<<<dim3(HIDDEN / 128, HWN / 128, BB), 256, 0, stream>>>(wo2, fused2, bo, out);
}

// Round 27
// 140.184 us; speedup vs baseline: 1.2676x; 1.0324x over previous
//
#include <hip/hip_runtime.h>
#include <hip/hip_bf16.h>

#define BB 8
#define EMBED 384
#define NH 32
#define HD 12
#define HWN 1024
#define HIDDEN 512
#define KTOT 1536
#define SCALE 0.28867513459481287f

typedef __attribute__((ext_vector_type(8))) unsigned short ushort8;
typedef __attribute__((ext_vector_type(8))) short short8;
typedef __attribute__((ext_vector_type(4))) float f32x4;
typedef __attribute__((ext_vector_type(16))) float f32x16;
typedef __attribute__((ext_vector_type(4))) unsigned short ushort4v;
typedef __attribute__((ext_vector_type(2))) unsigned int uint2v;

static __device__ __forceinline__ float bf2f(unsigned short u) {
    return __uint_as_float(((unsigned int)u) << 16);
}
static __device__ __forceinline__ unsigned short f2bf(float f) {
    unsigned int u = __float_as_uint(f);
    u = u + 0x7FFFu + ((u >> 16) & 1u);   // RNE
    return (unsigned short)(u >> 16);
}
static __device__ __forceinline__ unsigned int cvt_pk_bf16(float lo, float hi) {
    unsigned int r;
    asm("v_cvt_pk_bf16_f32 %0, %1, %2" : "=v"(r) : "v"(lo), "v"(hi));
    return r;
}

#if __has_builtin(__builtin_amdgcn_global_load_lds)
#define HAVE_GLOAD_LDS 1
static __device__ __forceinline__ void gl_lds16(const unsigned short* g, unsigned short* l) {
    __builtin_amdgcn_global_load_lds(
        (const __attribute__((address_space(1))) unsigned int*)g,
        (__attribute__((address_space(3))) unsigned int*)l, 16, 0, 0);
}
#else
#define HAVE_GLOAD_LDS 0
#endif

// ---------------- f32 -> bf16 weights; Wo duplicated into Wo2[512][1536] ----------------
struct WConv {
    const float* src[7];
    unsigned short* dst[7];
    int start[8];   // prefix over vec4 counts
};

__global__ __launch_bounds__(256) void k_bf16_all(WConv wc) {
    int i = blockIdx.x * 256 + threadIdx.x;
    if (i >= wc.start[7]) return;
    int p = 0;
#pragma unroll
    for (int j = 1; j < 7; ++j) p += (i >= wc.start[j]);
    const int e = i - wc.start[p];
    const f32x4 v = reinterpret_cast<const f32x4*>(wc.src[p])[e];
    ushort4v o;
#pragma unroll
    for (int j = 0; j < 4; ++j) o[j] = f2bf(v[j]);
    if (p == 6) {
        const int row = e / 192, cc = e % 192;
        ushort4v* d = reinterpret_cast<ushort4v*>(wc.dst[6]);
        d[row * 384 + cc] = o;
        d[row * 384 + 192 + cc] = o;
    } else {
        reinterpret_cast<ushort4v*>(wc.dst[p])[e] = o;
    }
}

// ---------------- transpose x (B,C,HW) f32 -> fused2[b][n][768 + s*384 + c] bf16 ----------------
__global__ __launch_bounds__(256) void k_transpose(const float* __restrict__ x0, const float* __restrict__ x1,
                                                   unsigned short* __restrict__ fused2) {
    __shared__ float tile[32][33];
    const int z = blockIdx.z;
    const int s = z >> 3, b = z & 7;
    const float* src = (s ? x1 : x0) + (size_t)b * EMBED * HWN;
    unsigned short* dst = fused2 + (size_t)b * HWN * KTOT + 768 + s * 384;
    const int c0 = blockIdx.x * 32;
    const int n0 = blockIdx.y * 32;
    const int tc = threadIdx.x & 31;
    const int tr = threadIdx.x >> 5;
#pragma unroll
    for (int p = 0; p < 4; ++p) {
        int r = tr + p * 8;
        tile[r][tc] = src[(size_t)(c0 + r) * HWN + n0 + tc];
    }
    __syncthreads();
#pragma unroll
    for (int p = 0; p < 4; ++p) {
        int r = tr + p * 8;
        dst[(size_t)(n0 + r) * KTOT + c0 + tc] = f2bf(tile[tc][r]);
    }
}

// ---------------- bf16 MFMA GEMM 128x128xBK64 + XOR swizzle (round-24 verified) ----------------
template <bool F32OUT>
static __device__ __forceinline__ void gemm128(const unsigned short* __restrict__ A, int lda,
                                               const unsigned short* __restrict__ Bt, int ldb,
                                               const float* __restrict__ bias,
                                               unsigned short* __restrict__ outBf,
                                               float* __restrict__ outF,
                                               int K, int bx, int by) {
    __shared__ unsigned short As[128][64];
    __shared__ unsigned short Bs[128][64];
    const int t = threadIdx.x;
    const int lane = t & 63;
    const int w = t >> 6;
    const int wr = w >> 1, wc = w & 1;
    const int o0 = bx * 128, n0 = by * 128;
    const int srow = lane >> 3;                              // 0..7 within chunk
    const int scol = (((lane & 7) ^ (lane >> 3)) << 3);      // swizzled source col (elements)

    f32x4 acc[4][4] = {};

    for (int k0 = 0; k0 < K; k0 += 64) {
#pragma unroll
        for (int i = 0; i < 4; ++i) {
            const int c = w * 4 + i;
            const int r = c * 8 + srow;
#if HAVE_GLOAD_LDS
            gl_lds16(A + (size_t)(o0 + r) * lda + k0 + scol, &As[c * 8][0]);
            gl_lds16(Bt + (size_t)(n0 + r) * ldb + k0 + scol, &Bs[c * 8][0]);
#else
            *reinterpret_cast<ushort8*>(&As[r][(lane & 7) * 8]) =
                *reinterpret_cast<const ushort8*>(A + (size_t)(o0 + r) * lda + k0 + scol);
            *reinterpret_cast<ushort8*>(&Bs[r][(lane & 7) * 8]) =
                *reinterpret_cast<const ushort8*>(Bt + (size_t)(n0 + r) * ldb + k0 + scol);
#endif
        }
        __syncthreads();
#pragma unroll
        for (int kk = 0; kk < 2; ++kk) {
            const int ko = kk * 32 + ((lane >> 4) << 3);
            const int xorb = (lane & 7) << 4;   // (R&7)<<4, R&7 == lane&7 for all frags
            short8 af[4], bf[4];
#pragma unroll
            for (int i = 0; i < 4; ++i) {
                const int ra = wr * 64 + i * 16 + (lane & 15);
                const int rb = wc * 64 + i * 16 + (lane & 15);
                af[i] = *reinterpret_cast<const short8*>(
                    reinterpret_cast<const char*>(&As[0][0]) + ra * 128 + ((ko * 2) ^ xorb));
                bf[i] = *reinterpret_cast<const short8*>(
                    reinterpret_cast<const char*>(&Bs[0][0]) + rb * 128 + ((ko * 2) ^ xorb));
            }
#pragma unroll
            for (int i = 0; i < 4; ++i)
#pragma unroll
                for (int j = 0; j < 4; ++j)
                    acc[i][j] = __builtin_amdgcn_mfma_f32_16x16x32_bf16(af[i], bf[j], acc[i][j], 0, 0, 0);
        }
        __syncthreads();
    }
#pragma unroll
    for (int i = 0; i < 4; ++i) {
#pragma unroll
        for (int j = 0; j < 4; ++j) {
            const int ob = o0 + wr * 64 + i * 16 + ((lane >> 4) << 2);
            const int n  = n0 + wc * 64 + j * 16 + (lane & 15);
#pragma unroll
            for (int r = 0; r < 4; ++r) {
                const int o = ob + r;
                float v = acc[i][j][r] + bias[o];
                if constexpr (F32OUT) outF[(size_t)o * HWN + n] = v;
                else                  outBf[(size_t)o * HWN + n] = f2bf(v);
            }
        }
    }
}

struct QkvTable {
    const unsigned short* W[6];
    const float* bias[6];
    const unsigned short* fused2;
    unsigned short* out[6];
};

// 1D grid 1152, XCD-local decode: the 3 M-tile blocks of each (n-tile, b, p) land on ONE XCD
// (bids congruent mod 8) so they share the Bt panel in that XCD's L2.
__global__ __launch_bounds__(256) void k_gemm_qkv(QkvTable tab) {
    const int bid = blockIdx.x;              // 0..1151
    const int xcd = bid & 7;
    const int slot = bid >> 3;               // 0..143
    const int bx = slot % 3;                 // M-tile
    const int g = (slot / 3) * 8 + xcd;      // 0..383 = (n-tile, z) group
    const int by = g & 7;                    // N-tile
    const int z = g >> 3;                    // 0..47
    const int b = z / 6, p = z % 6;
    const unsigned short* Bt = tab.fused2 + (size_t)b * HWN * KTOT + 768 + (p / 3) * 384;
    gemm128<false>(tab.W[p], EMBED, Bt, KTOT, tab.bias[p],
                   tab.out[p] + (size_t)b * EMBED * HWN, nullptr,
                   EMBED, bx, by);
}

// 1D grid 256, XCD-local decode: the 4 M-tile blocks of each (n-tile, b) share one XCD ->
// the 384KB fused2 B-panel is fetched once per XCD instead of 4x from HBM.
__global__ __launch_bounds__(256) void k_gemm_out(const unsigned short* __restrict__ Wo2,
                                                  const unsigned short* __restrict__ fused2,
                                                  const float* __restrict__ bo,
                                                  float* __restrict__ out) {
    const int bid = blockIdx.x;              // 0..255
    const int xcd = bid & 7;
    const int slot = bid >> 3;               // 0..31
    const int bx = slot & 3;                 // M-tile
    const int g = ((slot >> 2) << 3) | xcd;  // 0..63
    const int by = g & 7;                    // N-tile
    const int b = g >> 3;                    // batch
    gemm128<true>(Wo2, KTOT, fused2 + (size_t)b * HWN * KTOT, KTOT, bo,
                  nullptr, out + (size_t)b * HIDDEN * HWN,
                  KTOT, bx, by);
}

// ---------------- MFMA flash attention v11.1 (round-26 verified): 256 q/block, 8 waves ----------------
#define OT_STRIDE 416
__global__ __launch_bounds__(512) void k_attn_mfma(const unsigned short* __restrict__ qc,
                                                   const unsigned short* __restrict__ kc,
                                                   const unsigned short* __restrict__ vc,
                                                   const unsigned short* __restrict__ qcb,
                                                   const unsigned short* __restrict__ kcb,
                                                   const unsigned short* __restrict__ vcb,
                                                   unsigned short* __restrict__ fused2) {
    __shared__ unsigned short Ks[256][18];   // [m][d 0..15 + 2 pad], 36B rows (9 dw, coprime 32)
    __shared__ unsigned short Vs[13][264];   // [d][m], row 12 = ones

    const int bid = blockIdx.x;
    const int inst = bid & 511, qt = bid >> 9;      // blocks sharing inst are 512 apart -> same XCD
    const int branch = inst >> 8, b = (inst >> 5) & 7, h = inst & 31;
    const unsigned short* Qg = branch ? qc : qcb;
    const unsigned short* Kg = branch ? kcb : kc;
    const unsigned short* Vg = branch ? vcb : vc;
    const int coff = branch ? 384 : 0;
    const size_t base = ((size_t)b * EMBED + h * HD) * HWN;
    const int t = threadIdx.x;
    const int lane = t & 63, w = t >> 6;            // w = 0..7
    const int q31 = lane & 31, hi = lane >> 5;
    const int n0 = qt * 256;
    const float C2 = SCALE * 1.4426950408889634f;

    // Q B-frag (32x32x16): lane (q31,hi) holds Q[d=hi*8+j][q = n0 + w*32 + q31], pre-scaled by C2
    short8 qf = {};
    {
        const int qg = n0 + w * 32 + q31;
#pragma unroll
        for (int j = 0; j < 8; ++j) {
            const int d = hi * 8 + j;
            if (d < HD)
                qf[j] = (short)f2bf(bf2f(Qg[base + (size_t)d * HWN + qg]) * C2);
        }
    }

    f32x16 acc, z16;
#pragma unroll
    for (int r = 0; r < 16; ++r) { acc[r] = 0.f; z16[r] = 0.f; }
    const int vrow = (q31 < HD) ? q31 : 12;   // lanes d>=12 read ones row (outputs discarded)

    for (int phase = 0; phase < 4; ++phase) {
        const int m0 = phase << 8;
        __syncthreads();   // prior-phase reads done
        // --- stage K (256 m): waves 0-5 own d-pair (2w, 2w+1) -> dword col w; waves 6/7 zero cols 12-15
        if (w < 6) {
            const size_t kb = base + (size_t)(2 * w) * HWN + m0;
#pragma unroll
            for (int it = 0; it < 4; ++it) {
                const int m = it * 64 + lane;
                const unsigned int da = (unsigned int)Kg[kb + m] | ((unsigned int)Kg[kb + HWN + m] << 16);
                *reinterpret_cast<unsigned int*>(&Ks[m][2 * w]) = da;
            }
        } else {
            const int cz = 12 + 2 * (w - 6);   // cols 12-13 (w=6) / 14-15 (w=7)
#pragma unroll
            for (int it = 0; it < 4; ++it) {
                const int m = it * 64 + lane;
                *reinterpret_cast<unsigned int*>(&Ks[m][cz]) = 0u;
            }
        }
        // --- stage V (256 m): waves 0-5 own V rows 2w + (lane>>5); wave 6 lanes<32 write ones row
        if (w < 6) {
            const int d = 2 * w + (lane >> 5);
            const int col = (lane & 31) * 8;
            *reinterpret_cast<ushort8*>(&Vs[d][col]) =
                *reinterpret_cast<const ushort8*>(&Vg[base + (size_t)d * HWN + m0 + col]);
        } else if (w == 6 && lane < 32) {
            ushort8 ones;
#pragma unroll
            for (int j = 0; j < 8; ++j) ones[j] = 0x3F80;
            *reinterpret_cast<ushort8*>(&Vs[12][lane * 8]) = ones;
        }
        __syncthreads();

        __builtin_amdgcn_s_setprio(1);
        for (int mc = 0; mc < 8; ++mc) {
            const int mb = mc << 5;
            // K A-frag: lane (m-local = q31, hi) = K[mb+q31][d = hi*8+j]; dword loads (36B rows)
            union { short8 v; unsigned int u[4]; } kf;
            {
                const unsigned int* kp = reinterpret_cast<const unsigned int*>(&Ks[mb + q31][hi * 8]);
                kf.u[0] = kp[0]; kf.u[1] = kp[1]; kf.u[2] = kp[2]; kf.u[3] = kp[3];
            }
            // V B-frags, sigma-permuted k-rows: PV1 m {0..3,8..11}+4hi, PV2 +16
            union { short8 v; uint2v u2[2]; } vf1, vf2;
            vf1.u2[0] = *reinterpret_cast<const uint2v*>(&Vs[vrow][mb + hi * 4]);
            vf1.u2[1] = *reinterpret_cast<const uint2v*>(&Vs[vrow][mb + 8 + hi * 4]);
            vf2.u2[0] = *reinterpret_cast<const uint2v*>(&Vs[vrow][mb + 16 + hi * 4]);
            vf2.u2[1] = *reinterpret_cast<const uint2v*>(&Vs[vrow][mb + 24 + hi * 4]);
            // QKT: C reg r = P[m=(r&3)+8*(r>>2)+4hi][q=q31]
            const f32x16 s = __builtin_amdgcn_mfma_f32_32x32x16_bf16(kf.v, qf, z16, 0, 0, 0);
            union { short8 v; unsigned int u[4]; } p1, p2;
#pragma unroll
            for (int r = 0; r < 4; ++r) {
                p1.u[r] = cvt_pk_bf16(__builtin_amdgcn_exp2f(s[2 * r]),
                                      __builtin_amdgcn_exp2f(s[2 * r + 1]));
                p2.u[r] = cvt_pk_bf16(__builtin_amdgcn_exp2f(s[8 + 2 * r]),
                                      __builtin_amdgcn_exp2f(s[8 + 2 * r + 1]));
            }
            acc = __builtin_amdgcn_mfma_f32_32x32x16_bf16(p1.v, vf1.v, acc, 0, 0, 0);
            acc = __builtin_amdgcn_mfma_f32_32x32x16_bf16(p2.v, vf2.v, acc, 0, 0, 0);
        }
        __builtin_amdgcn_s_setprio(0);
    }

    // inverse row-sums: output col 12 (ones row) at lane (lane&32)|12, same reg
    float invq[16];
#pragma unroll
    for (int r = 0; r < 16; ++r)
        invq[r] = 1.0f / __shfl(acc[r], (lane & 32) | 12);

    __syncthreads();   // all Ks/Vs reads done before Ot overwrites Ks
    // Ot per wave: [12 d][32 q] shorts at stride OT_STRIDE, block index = w (0..7)
    {
        unsigned short* OtW = &Ks[0][0] + w * OT_STRIDE;
        if (q31 < HD) {
#pragma unroll
            for (int r2 = 0; r2 < 8; ++r2) {
                const int r = 2 * r2;
                const int q = (r & 3) + 8 * (r >> 2) + 4 * hi;
                const unsigned int dw = (unsigned int)f2bf(acc[r] * invq[r]) |
                                        ((unsigned int)f2bf(acc[r + 1] * invq[r + 1]) << 16);
                *reinterpret_cast<unsigned int*>(&OtW[q31 * 32 + q]) = dw;
            }
        }
    }
    __syncthreads();
    // store: 256 q, 512 threads: q = t>>1, half = t&1 covers d 0..5 / 6..11
    {
        const int q = t >> 1, half = t & 1;
        const unsigned short* Osrc = &Ks[0][0] + (q >> 5) * OT_STRIDE + (half * 6) * 32 + (q & 31);
        unsigned int dwv[3];
#pragma unroll
        for (int dp = 0; dp < 3; ++dp)
            dwv[dp] = (unsigned int)Osrc[(2 * dp) * 32] | ((unsigned int)Osrc[(2 * dp + 1) * 32] << 16);
        unsigned int* dst = reinterpret_cast<unsigned int*>(
            fused2 + ((size_t)b * HWN + n0 + q) * KTOT + coff + h * HD + half * 6);
#pragma unroll
        for (int dp = 0; dp < 3; ++dp) dst[dp] = dwv[dp];
    }
}

extern "C" void kernel_launch(void* const* d_in, const int* in_sizes, int n_in,
                              void* d_out, int out_size, void* d_ws, size_t ws_size,
                              hipStream_t stream) {
    (void)in_sizes; (void)n_in; (void)out_size; (void)ws_size;
    const float* x   = (const float*)d_in[0];
    const float* xbp = (const float*)d_in[1];
    const float* Wq  = (const float*)d_in[2];  const float* bq  = (const float*)d_in[3];
    const float* Wk  = (const float*)d_in[4];  const float* bk  = (const float*)d_in[5];
    const float* Wv  = (const float*)d_in[6];  const float* bv  = (const float*)d_in[7];
    const float* Wqb = (const float*)d_in[8];  const float* bqb = (const float*)d_in[9];
    const float* Wkb = (const float*)d_in[10]; const float* bkb = (const float*)d_in[11];
    const float* Wvb = (const float*)d_in[12]; const float* bvb = (const float*)d_in[13];
    const float* Wo  = (const float*)d_in[14]; const float* bo  = (const float*)d_in[15];
    float* out = (float*)d_out;

    char* ws = (char*)d_ws;
    size_t off = 0;
    auto alloc = [&](size_t bytes) -> void* {
        void* p = ws + off;
        off = (off + bytes + 255) & ~(size_t)255;
        return p;
    };
    unsigned short* wbf[6];
    for (int i = 0; i < 6; ++i) wbf[i] = (unsigned short*)alloc((size_t)EMBED * EMBED * 2);
    unsigned short* wo2 = (unsigned short*)alloc((size_t)HIDDEN * KTOT * 2);
    unsigned short* qkv[6];
    for (int i = 0; i < 6; ++i) qkv[i] = (unsigned short*)alloc((size_t)BB * EMBED * HWN * 2);
    unsigned short* fused2 = (unsigned short*)alloc((size_t)BB * HWN * KTOT * 2);

    // 1) weights -> bf16 (Wo duplicated into Wo2)
    WConv wc;
    const float* wsrc[7] = {Wq, Wk, Wv, Wqb, Wkb, Wvb, Wo};
    unsigned short* wdst[7] = {wbf[0], wbf[1], wbf[2], wbf[3], wbf[4], wbf[5], wo2};
    int acc4 = 0;
    for (int i = 0; i < 7; ++i) {
        const int n = (i < 6) ? EMBED * EMBED : HIDDEN * 768;
        wc.src[i] = wsrc[i];
        wc.dst[i] = wdst[i];
        wc.start[i] = acc4;
        acc4 += n / 4;
    }
    wc.start[7] = acc4;
    k_bf16_all<<<(acc4 + 255) / 256, 256, 0, stream>>>(wc);

    // 2) x, x_bpf -> token-major bf16 into fused2 cols 768..1535
    k_transpose<<<dim3(EMBED / 32, HWN / 32, 16), 256, 0, stream>>>(x, xbp, fused2);

    // 3) six QKV projections (128x128 tiles, 1D grid with XCD-local decode)
    QkvTable tab;
    tab.W[0] = wbf[0]; tab.W[1] = wbf[1]; tab.W[2] = wbf[2];
    tab.W[3] = wbf[3]; tab.W[4] = wbf[4]; tab.W[5] = wbf[5];
    tab.bias[0] = bq; tab.bias[1] = bk; tab.bias[2] = bv;
    tab.bias[3] = bqb; tab.bias[4] = bkb; tab.bias[5] = bvb;
    tab.fused2 = fused2;
    for (int i = 0; i < 6; ++i) tab.out[i] = qkv[i];
    k_gemm_qkv<<<dim3(1152), 256, 0, stream>>>(tab);

    // 4) MFMA attention -> fused2 cols 0..767 (512 instances x 4 q-tiles of 256, 8-wave blocks)
    k_attn_mfma<<<dim3(2048), 512, 0, stream>>>(qkv[0], qkv[1], qkv[2], qkv[3], qkv[4], qkv[5],
                                                fused2);

    // 5) out = Wo2 . fused2 + bo   (K=1536 folds the residual; 1D grid with XCD-local decode)
    k_gemm_out<<<dim3(256), 256, 0, stream>>>(wo2, fused2, bo, out);
}

// Round 28
// 136.768 us; speedup vs baseline: 1.2993x; 1.0250x over previous
//
#include <hip/hip_runtime.h>
#include <hip/hip_bf16.h>

#define BB 8
#define EMBED 384
#define NH 32
#define HD 12
#define HWN 1024
#define HIDDEN 512
#define KTOT 1536
#define SCALE 0.28867513459481287f

typedef __attribute__((ext_vector_type(8))) unsigned short ushort8;
typedef __attribute__((ext_vector_type(8))) short short8;
typedef __attribute__((ext_vector_type(4))) float f32x4;
typedef __attribute__((ext_vector_type(16))) float f32x16;
typedef __attribute__((ext_vector_type(4))) unsigned short ushort4v;
typedef __attribute__((ext_vector_type(2))) unsigned int uint2v;

static __device__ __forceinline__ float bf2f(unsigned short u) {
    return __uint_as_float(((unsigned int)u) << 16);
}
static __device__ __forceinline__ unsigned short f2bf(float f) {
    unsigned int u = __float_as_uint(f);
    u = u + 0x7FFFu + ((u >> 16) & 1u);   // RNE
    return (unsigned short)(u >> 16);
}
static __device__ __forceinline__ unsigned int cvt_pk_bf16(float lo, float hi) {
    unsigned int r;
    asm("v_cvt_pk_bf16_f32 %0, %1, %2" : "=v"(r) : "v"(lo), "v"(hi));
    return r;
}

#if __has_builtin(__builtin_amdgcn_global_load_lds)
#define HAVE_GLOAD_LDS 1
static __device__ __forceinline__ void gl_lds16(const unsigned short* g, unsigned short* l) {
    __builtin_amdgcn_global_load_lds(
        (const __attribute__((address_space(1))) unsigned int*)g,
        (__attribute__((address_space(3))) unsigned int*)l, 16, 0, 0);
}
#else
#define HAVE_GLOAD_LDS 0
#endif

// ---------------- f32 -> bf16 weights; Wo duplicated into Wo2[512][1536] ----------------
struct WConv {
    const float* src[7];
    unsigned short* dst[7];
    int start[8];   // prefix over vec4 counts
};

__global__ __launch_bounds__(256) void k_bf16_all(WConv wc) {
    int i = blockIdx.x * 256 + threadIdx.x;
    if (i >= wc.start[7]) return;
    int p = 0;
#pragma unroll
    for (int j = 1; j < 7; ++j) p += (i >= wc.start[j]);
    const int e = i - wc.start[p];
    const f32x4 v = reinterpret_cast<const f32x4*>(wc.src[p])[e];
    ushort4v o;
#pragma unroll
    for (int j = 0; j < 4; ++j) o[j] = f2bf(v[j]);
    if (p == 6) {
        const int row = e / 192, cc = e % 192;
        ushort4v* d = reinterpret_cast<ushort4v*>(wc.dst[6]);
        d[row * 384 + cc] = o;
        d[row * 384 + 192 + cc] = o;
    } else {
        reinterpret_cast<ushort4v*>(wc.dst[p])[e] = o;
    }
}

// ---------------- transpose x (B,C,HW) f32 -> fused2[b][n][768 + s*384 + c] bf16 ----------------
__global__ __launch_bounds__(256) void k_transpose(const float* __restrict__ x0, const float* __restrict__ x1,
                                                   unsigned short* __restrict__ fused2) {
    __shared__ float tile[32][33];
    const int z = blockIdx.z;
    const int s = z >> 3, b = z & 7;
    const float* src = (s ? x1 : x0) + (size_t)b * EMBED * HWN;
    unsigned short* dst = fused2 + (size_t)b * HWN * KTOT + 768 + s * 384;
    const int c0 = blockIdx.x * 32;
    const int n0 = blockIdx.y * 32;
    const int tc = threadIdx.x & 31;
    const int tr = threadIdx.x >> 5;
#pragma unroll
    for (int p = 0; p < 4; ++p) {
        int r = tr + p * 8;
        tile[r][tc] = src[(size_t)(c0 + r) * HWN + n0 + tc];
    }
    __syncthreads();
#pragma unroll
    for (int p = 0; p < 4; ++p) {
        int r = tr + p * 8;
        dst[(size_t)(n0 + r) * KTOT + c0 + tc] = f2bf(tile[tc][r]);
    }
}

// ---------------- bf16 MFMA GEMM 128x128xBK64 + XOR swizzle (round-24 verified) ----------------
template <bool F32OUT>
static __device__ __forceinline__ void gemm128(const unsigned short* __restrict__ A, int lda,
                                               const unsigned short* __restrict__ Bt, int ldb,
                                               const float* __restrict__ bias,
                                               unsigned short* __restrict__ outBf,
                                               float* __restrict__ outF,
                                               int K, int bx, int by) {
    __shared__ unsigned short As[128][64];
    __shared__ unsigned short Bs[128][64];
    const int t = threadIdx.x;
    const int lane = t & 63;
    const int w = t >> 6;
    const int wr = w >> 1, wc = w & 1;
    const int o0 = bx * 128, n0 = by * 128;
    const int srow = lane >> 3;                              // 0..7 within chunk
    const int scol = (((lane & 7) ^ (lane >> 3)) << 3);      // swizzled source col (elements)

    f32x4 acc[4][4] = {};

    for (int k0 = 0; k0 < K; k0 += 64) {
#pragma unroll
        for (int i = 0; i < 4; ++i) {
            const int c = w * 4 + i;
            const int r = c * 8 + srow;
#if HAVE_GLOAD_LDS
            gl_lds16(A + (size_t)(o0 + r) * lda + k0 + scol, &As[c * 8][0]);
            gl_lds16(Bt + (size_t)(n0 + r) * ldb + k0 + scol, &Bs[c * 8][0]);
#else
            *reinterpret_cast<ushort8*>(&As[r][(lane & 7) * 8]) =
                *reinterpret_cast<const ushort8*>(A + (size_t)(o0 + r) * lda + k0 + scol);
            *reinterpret_cast<ushort8*>(&Bs[r][(lane & 7) * 8]) =
                *reinterpret_cast<const ushort8*>(Bt + (size_t)(n0 + r) * ldb + k0 + scol);
#endif
        }
        __syncthreads();
#pragma unroll
        for (int kk = 0; kk < 2; ++kk) {
            const int ko = kk * 32 + ((lane >> 4) << 3);
            const int xorb = (lane & 7) << 4;   // (R&7)<<4, R&7 == lane&7 for all frags
            short8 af[4], bf[4];
#pragma unroll
            for (int i = 0; i < 4; ++i) {
                const int ra = wr * 64 + i * 16 + (lane & 15);
                const int rb = wc * 64 + i * 16 + (lane & 15);
                af[i] = *reinterpret_cast<const short8*>(
                    reinterpret_cast<const char*>(&As[0][0]) + ra * 128 + ((ko * 2) ^ xorb));
                bf[i] = *reinterpret_cast<const short8*>(
                    reinterpret_cast<const char*>(&Bs[0][0]) + rb * 128 + ((ko * 2) ^ xorb));
            }
#pragma unroll
            for (int i = 0; i < 4; ++i)
#pragma unroll
                for (int j = 0; j < 4; ++j)
                    acc[i][j] = __builtin_amdgcn_mfma_f32_16x16x32_bf16(af[i], bf[j], acc[i][j], 0, 0, 0);
        }
        __syncthreads();
    }
#pragma unroll
    for (int i = 0; i < 4; ++i) {
#pragma unroll
        for (int j = 0; j < 4; ++j) {
            const int ob = o0 + wr * 64 + i * 16 + ((lane >> 4) << 2);
            const int n  = n0 + wc * 64 + j * 16 + (lane & 15);
#pragma unroll
            for (int r = 0; r < 4; ++r) {
                const int o = ob + r;
                float v = acc[i][j][r] + bias[o];
                if constexpr (F32OUT) outF[(size_t)o * HWN + n] = v;
                else                  outBf[(size_t)o * HWN + n] = f2bf(v);
            }
        }
    }
}

struct QkvTable {
    const unsigned short* W[6];
    const float* bias[6];
    const unsigned short* fused2;
    unsigned short* out[6];
};

// 1D grid 1152, XCD-local decode (round-27 verified)
__global__ __launch_bounds__(256) void k_gemm_qkv(QkvTable tab) {
    const int bid = blockIdx.x;              // 0..1151
    const int xcd = bid & 7;
    const int slot = bid >> 3;               // 0..143
    const int bx = slot % 3;                 // M-tile
    const int g = (slot / 3) * 8 + xcd;      // 0..383
    const int by = g & 7;                    // N-tile
    const int z = g >> 3;                    // 0..47
    const int b = z / 6, p = z % 6;
    const unsigned short* Bt = tab.fused2 + (size_t)b * HWN * KTOT + 768 + (p / 3) * 384;
    gemm128<false>(tab.W[p], EMBED, Bt, KTOT, tab.bias[p],
                   tab.out[p] + (size_t)b * EMBED * HWN, nullptr,
                   EMBED, bx, by);
}

// 1D grid 256, XCD-local decode (round-27 verified)
__global__ __launch_bounds__(256) void k_gemm_out(const unsigned short* __restrict__ Wo2,
                                                  const unsigned short* __restrict__ fused2,
                                                  const float* __restrict__ bo,
                                                  float* __restrict__ out) {
    const int bid = blockIdx.x;              // 0..255
    const int xcd = bid & 7;
    const int slot = bid >> 3;               // 0..31
    const int bx = slot & 3;                 // M-tile
    const int g = ((slot >> 2) << 3) | xcd;  // 0..63
    const int by = g & 7;                    // N-tile
    const int b = g >> 3;                    // batch
    gemm128<true>(Wo2, KTOT, fused2 + (size_t)b * HWN * KTOT, KTOT, bo,
                  nullptr, out + (size_t)b * HIDDEN * HWN,
                  KTOT, bx, by);
}

// ---------------- MFMA flash attention v12: v11.1 + T14 async-STAGE split + LDS double-buffer ----------------
// Per phase: issue phase p+1's global loads to REGS before compute(p) (HBM latency hides under
// the mc loop), ds_write them to buf^1 AFTER compute(p); ONE barrier per phase. K-pad zeros and
// ones-row written once in the prologue (never overwritten in-loop).
#define OT_STRIDE 416
__global__ __launch_bounds__(512) void k_attn_mfma(const unsigned short* __restrict__ qc,
                                                   const unsigned short* __restrict__ kc,
                                                   const unsigned short* __restrict__ vc,
                                                   const unsigned short* __restrict__ qcb,
                                                   const unsigned short* __restrict__ kcb,
                                                   const unsigned short* __restrict__ vcb,
                                                   unsigned short* __restrict__ fused2) {
    __shared__ unsigned short Ks[2][256][18];   // [buf][m][d 0..15 + 2 pad], 36B rows
    __shared__ unsigned short Vs[2][13][264];   // [buf][d][m], row 12 = ones

    const int bid = blockIdx.x;
    const int inst = bid & 511, qt = bid >> 9;      // blocks sharing inst are 512 apart -> same XCD
    const int branch = inst >> 8, b = (inst >> 5) & 7, h = inst & 31;
    const unsigned short* Qg = branch ? qc : qcb;
    const unsigned short* Kg = branch ? kcb : kc;
    const unsigned short* Vg = branch ? vcb : vc;
    const int coff = branch ? 384 : 0;
    const size_t base = ((size_t)b * EMBED + h * HD) * HWN;
    const int t = threadIdx.x;
    const int lane = t & 63, w = t >> 6;            // w = 0..7
    const int q31 = lane & 31, hi = lane >> 5;
    const int n0 = qt * 256;
    const float C2 = SCALE * 1.4426950408889634f;

    // Q B-frag (32x32x16): lane (q31,hi) holds Q[d=hi*8+j][q = n0 + w*32 + q31], pre-scaled by C2
    short8 qf = {};
    {
        const int qg = n0 + w * 32 + q31;
#pragma unroll
        for (int j = 0; j < 8; ++j) {
            const int d = hi * 8 + j;
            if (d < HD)
                qf[j] = (short)f2bf(bf2f(Qg[base + (size_t)d * HWN + qg]) * C2);
        }
    }

    // one-time fills: K cols 12-15 zero, V ones row (both buffers); never overwritten in-loop
    if (w >= 6) {
        const int cz = 12 + 2 * (w - 6);
#pragma unroll
        for (int buf = 0; buf < 2; ++buf)
#pragma unroll
            for (int it = 0; it < 4; ++it) {
                const int m = it * 64 + lane;
                *reinterpret_cast<unsigned int*>(&Ks[buf][m][cz]) = 0u;
            }
    }
    if (w == 6 && lane < 32) {
        ushort8 ones;
#pragma unroll
        for (int j = 0; j < 8; ++j) ones[j] = 0x3F80;
        *reinterpret_cast<ushort8*>(&Vs[0][12][lane * 8]) = ones;
        *reinterpret_cast<ushort8*>(&Vs[1][12][lane * 8]) = ones;
    }

    f32x16 acc, z16;
#pragma unroll
    for (int r = 0; r < 16; ++r) { acc[r] = 0.f; z16[r] = 0.f; }
    const int vrow = (q31 < HD) ? q31 : 12;

    // staging registers (statically indexed)
    unsigned short kr0, kr1, kr2, kr3, kr4, kr5, kr6, kr7;
    ushort8 vreg = {};

    // LOADS(phase): issue global loads into regs (waves 0-5 only)
    auto LOADS = [&](int phase) {
        if (w < 6) {
            const int m0 = phase << 8;
            const size_t kb = base + (size_t)(2 * w) * HWN + m0;
            kr0 = Kg[kb + lane];           kr1 = Kg[kb + HWN + lane];
            kr2 = Kg[kb + 64 + lane];      kr3 = Kg[kb + HWN + 64 + lane];
            kr4 = Kg[kb + 128 + lane];     kr5 = Kg[kb + HWN + 128 + lane];
            kr6 = Kg[kb + 192 + lane];     kr7 = Kg[kb + HWN + 192 + lane];
            const int d = 2 * w + (lane >> 5);
            vreg = *reinterpret_cast<const ushort8*>(&Vg[base + (size_t)d * HWN + m0 + (lane & 31) * 8]);
        }
    };
    // WRITES(buf): commit regs to LDS buffer
    auto WRITES = [&](int buf) {
        if (w < 6) {
            *reinterpret_cast<unsigned int*>(&Ks[buf][lane][2 * w])       = (unsigned int)kr0 | ((unsigned int)kr1 << 16);
            *reinterpret_cast<unsigned int*>(&Ks[buf][64 + lane][2 * w])  = (unsigned int)kr2 | ((unsigned int)kr3 << 16);
            *reinterpret_cast<unsigned int*>(&Ks[buf][128 + lane][2 * w]) = (unsigned int)kr4 | ((unsigned int)kr5 << 16);
            *reinterpret_cast<unsigned int*>(&Ks[buf][192 + lane][2 * w]) = (unsigned int)kr6 | ((unsigned int)kr7 << 16);
            const int d = 2 * w + (lane >> 5);
            *reinterpret_cast<ushort8*>(&Vs[buf][d][(lane & 31) * 8]) = vreg;
        }
    };

    LOADS(0);
    WRITES(0);
    for (int phase = 0; phase < 4; ++phase) {
        if (phase < 3) LOADS(phase + 1);    // issue-early: latency hides under compute below
        __syncthreads();                    // buf[phase&1] writes visible to all waves
        const int buf = phase & 1;

        __builtin_amdgcn_s_setprio(1);
        for (int mc = 0; mc < 8; ++mc) {
            const int mb = mc << 5;
            // K A-frag: lane (m-local = q31, hi) = K[mb+q31][d = hi*8+j]; dword loads (36B rows)
            union { short8 v; unsigned int u[4]; } kf;
            {
                const unsigned int* kp = reinterpret_cast<const unsigned int*>(&Ks[buf][mb + q31][hi * 8]);
                kf.u[0] = kp[0]; kf.u[1] = kp[1]; kf.u[2] = kp[2]; kf.u[3] = kp[3];
            }
            // V B-frags, sigma-permuted k-rows: PV1 m {0..3,8..11}+4hi, PV2 +16
            union { short8 v; uint2v u2[2]; } vf1, vf2;
            vf1.u2[0] = *reinterpret_cast<const uint2v*>(&Vs[buf][vrow][mb + hi * 4]);
            vf1.u2[1] = *reinterpret_cast<const uint2v*>(&Vs[buf][vrow][mb + 8 + hi * 4]);
            vf2.u2[0] = *reinterpret_cast<const uint2v*>(&Vs[buf][vrow][mb + 16 + hi * 4]);
            vf2.u2[1] = *reinterpret_cast<const uint2v*>(&Vs[buf][vrow][mb + 24 + hi * 4]);
            // QKT: C reg r = P[m=(r&3)+8*(r>>2)+4hi][q=q31]
            const f32x16 s = __builtin_amdgcn_mfma_f32_32x32x16_bf16(kf.v, qf, z16, 0, 0, 0);
            union { short8 v; unsigned int u[4]; } p1, p2;
#pragma unroll
            for (int r = 0; r < 4; ++r) {
                p1.u[r] = cvt_pk_bf16(__builtin_amdgcn_exp2f(s[2 * r]),
                                      __builtin_amdgcn_exp2f(s[2 * r + 1]));
                p2.u[r] = cvt_pk_bf16(__builtin_amdgcn_exp2f(s[8 + 2 * r]),
                                      __builtin_amdgcn_exp2f(s[8 + 2 * r + 1]));
            }
            acc = __builtin_amdgcn_mfma_f32_32x32x16_bf16(p1.v, vf1.v, acc, 0, 0, 0);
            acc = __builtin_amdgcn_mfma_f32_32x32x16_bf16(p2.v, vf2.v, acc, 0, 0, 0);
        }
        __builtin_amdgcn_s_setprio(0);

        if (phase < 3) WRITES((phase + 1) & 1);   // write-late: after this phase's compute
    }

    // inverse row-sums: output col 12 (ones row) at lane (lane&32)|12, same reg
    float invq[16];
#pragma unroll
    for (int r = 0; r < 16; ++r)
        invq[r] = 1.0f / __shfl(acc[r], (lane & 32) | 12);

    __syncthreads();   // all Ks/Vs reads done before Ot overwrites Ks
    // Ot per wave: [12 d][32 q] shorts at stride OT_STRIDE, block index = w (0..7)
    {
        unsigned short* OtW = &Ks[0][0][0] + w * OT_STRIDE;
        if (q31 < HD) {
#pragma unroll
            for (int r2 = 0; r2 < 8; ++r2) {
                const int r = 2 * r2;
                const int q = (r & 3) + 8 * (r >> 2) + 4 * hi;
                const unsigned int dw = (unsigned int)f2bf(acc[r] * invq[r]) |
                                        ((unsigned int)f2bf(acc[r + 1] * invq[r + 1]) << 16);
                *reinterpret_cast<unsigned int*>(&OtW[q31 * 32 + q]) = dw;
            }
        }
    }
    __syncthreads();
    // store: 256 q, 512 threads: q = t>>1, half = t&1 covers d 0..5 / 6..11
    {
        const int q = t >> 1, half = t & 1;
        const unsigned short* Osrc = &Ks[0][0][0] + (q >> 5) * OT_STRIDE + (half * 6) * 32 + (q & 31);
        unsigned int dwv[3];
#pragma unroll
        for (int dp = 0; dp < 3; ++dp)
            dwv[dp] = (unsigned int)Osrc[(2 * dp) * 32] | ((unsigned int)Osrc[(2 * dp + 1) * 32] << 16);
        unsigned int* dst = reinterpret_cast<unsigned int*>(
            fused2 + ((size_t)b * HWN + n0 + q) * KTOT + coff + h * HD + half * 6);
#pragma unroll
        for (int dp = 0; dp < 3; ++dp) dst[dp] = dwv[dp];
    }
}

extern "C" void kernel_launch(void* const* d_in, const int* in_sizes, int n_in,
                              void* d_out, int out_size, void* d_ws, size_t ws_size,
                              hipStream_t stream) {
    (void)in_sizes; (void)n_in; (void)out_size; (void)ws_size;
    const float* x   = (const float*)d_in[0];
    const float* xbp = (const float*)d_in[1];
    const float* Wq  = (const float*)d_in[2];  const float* bq  = (const float*)d_in[3];
    const float* Wk  = (const float*)d_in[4];  const float* bk  = (const float*)d_in[5];
    const float* Wv  = (const float*)d_in[6];  const float* bv  = (const float*)d_in[7];
    const float* Wqb = (const float*)d_in[8];  const float* bqb = (const float*)d_in[9];
    const float* Wkb = (const float*)d_in[10]; const float* bkb = (const float*)d_in[11];
    const float* Wvb = (const float*)d_in[12]; const float* bvb = (const float*)d_in[13];
    const float* Wo  = (const float*)d_in[14]; const float* bo  = (const float*)d_in[15];
    float* out = (float*)d_out;

    char* ws = (char*)d_ws;
    size_t off = 0;
    auto alloc = [&](size_t bytes) -> void* {
        void* p = ws + off;
        off = (off + bytes + 255) & ~(size_t)255;
        return p;
    };
    unsigned short* wbf[6];
    for (int i = 0; i < 6; ++i) wbf[i] = (unsigned short*)alloc((size_t)EMBED * EMBED * 2);
    unsigned short* wo2 = (unsigned short*)alloc((size_t)HIDDEN * KTOT * 2);
    unsigned short* qkv[6];
    for (int i = 0; i < 6; ++i) qkv[i] = (unsigned short*)alloc((size_t)BB * EMBED * HWN * 2);
    unsigned short* fused2 = (unsigned short*)alloc((size_t)BB * HWN * KTOT * 2);

    // 1) weights -> bf16 (Wo duplicated into Wo2)
    WConv wc;
    const float* wsrc[7] = {Wq, Wk, Wv, Wqb, Wkb, Wvb, Wo};
    unsigned short* wdst[7] = {wbf[0], wbf[1], wbf[2], wbf[3], wbf[4], wbf[5], wo2};
    int acc4 = 0;
    for (int i = 0; i < 7; ++i) {
        const int n = (i < 6) ? EMBED * EMBED : HIDDEN * 768;
        wc.src[i] = wsrc[i];
        wc.dst[i] = wdst[i];
        wc.start[i] = acc4;
        acc4 += n / 4;
    }
    wc.start[7] = acc4;
    k_bf16_all<<<(acc4 + 255) / 256, 256, 0, stream>>>(wc);

    // 2) x, x_bpf -> token-major bf16 into fused2 cols 768..1535
    k_transpose<<<dim3(EMBED / 32, HWN / 32, 16), 256, 0, stream>>>(x, xbp, fused2);

    // 3) six QKV projections (128x128 tiles, 1D grid with XCD-local decode)
    QkvTable tab;
    tab.W[0] = wbf[0]; tab.W[1] = wbf[1]; tab.W[2] = wbf[2];
    tab.W[3] = wbf[3]; tab.W[4] = wbf[4]; tab.W[5] = wbf[5];
    tab.bias[0] = bq; tab.bias[1] = bk; tab.bias[2] = bv;
    tab.bias[3] = bqb; tab.bias[4] = bkb; tab.bias[5] = bvb;
    tab.fused2 = fused2;
    for (int i = 0; i < 6; ++i) tab.out[i] = qkv[i];
    k_gemm_qkv<<<dim3(1152), 256, 0, stream>>>(tab);

    // 4) MFMA attention -> fused2 cols 0..767 (512 instances x 4 q-tiles of 256, 8-wave blocks)
    k_attn_mfma<<<dim3(2048), 512, 0, stream>>>(qkv[0], qkv[1], qkv[2], qkv[3], qkv[4], qkv[5],
                                                fused2);

    // 5) out = Wo2 . fused2 + bo   (K=1536 folds the residual; 1D grid with XCD-local decode)
    k_gemm_out<<<dim3(256), 256, 0, stream>>>(wo2, fused2, bo, out);
}